// Round 6
// baseline (350.882 us; speedup 1.0000x reference)
//
#include <hip/hip_runtime.h>
#include <hip/hip_bf16.h>

#define BATCH 1024
#define NV 5023
#define NJOINT 5
#define NLMK 51
#define N3 (NV*3)        // 15069
#define NPADB 15072      // N3 padded to multiple of 48
#define KBETA 400
#define KTOT 448         // 400 betas + 36 pose_feature + 12 zero pad

#define BM 256           // batches per block (4 waves x 64 rows)
#define BN 48            // output cols per block = 16 vertices
#define LDP 52           // LDS pitch (f32) for acc tile
#define NFRAG 2688       // 48*448/8 B-fragments per panel

typedef __attribute__((ext_vector_type(8))) short short8;
typedef __attribute__((ext_vector_type(4))) float floatx4;

// ---------------- workspace byte offsets ----------------
#define WS_JS      0          // 6000 f32
#define WS_BASEJ   24064      // 15 f32
#define WS_REG     24512      // 1 f32
#define WS_FLAGS   24520      // 2 ints
#define WS_AMAT    24576      // 1024*60 f32   -> ends 270336
#define WS_ACT     270336     // 1024*448 bf16 -> ends 1187840
#define WS_WB      1187840    // 15072*448 bf16 -> ends 14692352
#define WS_FULL    14692352

__device__ __forceinline__ float ldf(const void* p, long i, int f32) {
    if (f32) return ((const float*)p)[i];
    return __bfloat162float(((const __hip_bfloat16*)p)[i]);
}
__device__ __forceinline__ short8 ld8bf(const void* p, long i, int f32) {
    if (f32) {
        const float* q = (const float*)p + i;
        short8 r;
#pragma unroll
        for (int j = 0; j < 8; ++j) {
            __hip_bfloat16 h = __float2bfloat16(q[j]);
            r[j] = *reinterpret_cast<short*>(&h);
        }
        return r;
    }
    return *(const short8*)((const __hip_bfloat16*)p + i);
}
__device__ __forceinline__ void stf(void* p, long i, float v, int f32) {
    if (f32) ((float*)p)[i] = v;
    else ((__hip_bfloat16*)p)[i] = __float2bfloat16(v);
}
// nontemporal store (streaming 62 MB output: keep L2 for Wb/Act)
__device__ __forceinline__ void stf_nt(void* p, long i, float v, int f32) {
    if (f32) __builtin_nontemporal_store(v, (float*)p + i);
    else {
        __hip_bfloat16 h = __float2bfloat16(v);
        __builtin_nontemporal_store(*reinterpret_cast<short*>(&h), (short*)p + i);
    }
}

// zero JS/baseJ/reg (NOT flags) + dtype probe (block 0)
__global__ void k_init(float* ws0, const void* shape_p, const void* lmk_idx, int* flags) {
    int i = blockIdx.x * 256 + threadIdx.x;
    if (i < 6129) ws0[i] = 0.f;
    if (blockIdx.x == 0) {
        __shared__ float mx[64];
        int tid = threadIdx.x;
        if (tid < 64) {
            unsigned short h = ((const unsigned short*)shape_p)[2 * tid];
            union { unsigned short u; __hip_bfloat16 b; } cv; cv.u = h;
            float v = fabsf(__bfloat162float(cv.b));
            if (v != v) v = 3.4e38f;
            mx[tid] = v;
        }
        __syncthreads();
        if (tid == 0) {
            float m = 0.f;
            for (int j = 0; j < 64; ++j) m = fmaxf(m, mx[j]);
            flags[0] = (m > 1e4f) ? 1 : 0;
            int i64 = 1;
            const int* q = (const int*)lmk_idx;
            for (int j = 0; j < 25; ++j) if (q[2*j+1] != 0) i64 = 0;
            flags[1] = i64;
        }
    }
}

// Pack B panel bf16: Wb[n][k], k<400 shapedirs, 400..435 posedirs^T, else 0.
__global__ __launch_bounds__(448) void k_cvt(const void* __restrict__ shapedirs,
                                             const void* __restrict__ posedirs,
                                             const int* __restrict__ flags,
                                             __hip_bfloat16* __restrict__ Wb) {
    int f32 = flags[0];
    int n = blockIdx.x, k = threadIdx.x;
    float val = 0.f;
    if (n < N3) {
        if (k < KBETA)       val = ldf(shapedirs, (long)n*KBETA + k, f32);
        else if (k < 436)    val = ldf(posedirs, (long)(k-400)*N3 + n, f32);
    }
    Wb[(long)n*KTOT + k] = __float2bfloat16(val);
}

// JS[j][k][l] = sum_v Jreg[j][v]*shapedirs[v][k][l]; baseJ = Jreg @ v_template
__global__ void k_js(const void* __restrict__ Jreg,
                     const void* __restrict__ shapedirs,
                     const void* __restrict__ v_template,
                     const int* __restrict__ flags,
                     float* __restrict__ JS, float* __restrict__ baseJ) {
    int f32 = flags[0];
    int k = blockIdx.x;
    int vc = blockIdx.y;
    int tid = threadIdx.x;
    int v0 = vc * 79, v1 = min(NV, v0 + 79);
    int l2 = tid + 256;
    float acc1[NJOINT] = {0,0,0,0,0};
    float acc2[NJOINT] = {0,0,0,0,0};
#pragma unroll 2
    for (int v = v0; v < v1; ++v) {
        float s1 = ldf(shapedirs, (long)v*1200 + k*400 + tid, f32);
        float s2 = 0.f;
        if (l2 < 400)       s2 = ldf(shapedirs, (long)v*1200 + k*400 + l2, f32);
        else if (l2 == 400) s2 = ldf(v_template, v*3 + k, f32);
#pragma unroll
        for (int j = 0; j < NJOINT; ++j) {
            float jr = ldf(Jreg, j*NV + v, f32);
            acc1[j] += jr * s1;
            acc2[j] += jr * s2;
        }
    }
#pragma unroll
    for (int j = 0; j < NJOINT; ++j) {
        atomicAdd(&JS[j*1200 + k*400 + tid], acc1[j]);
        if (l2 < 400)       atomicAdd(&JS[j*1200 + k*400 + l2], acc2[j]);
        else if (l2 == 400) atomicAdd(&baseJ[j*3 + k], acc2[j]);
    }
}

// Per-batch: betas->Act(bf16), joints, rodrigues, chain, A matrices, reg
__global__ __launch_bounds__(64) void k_batch(
        const void* __restrict__ shape_p, const void* __restrict__ expr_p,
        const void* __restrict__ grot, const void* __restrict__ neck,
        const void* __restrict__ jaw,  const void* __restrict__ eye,
        const float* __restrict__ JS, const float* __restrict__ baseJ,
        const int* __restrict__ flags,
        __hip_bfloat16* __restrict__ Act, float* __restrict__ Amat, float* __restrict__ reg) {
    int f32 = flags[0];
    int b = blockIdx.x, tid = threadIdx.x;
    __shared__ float betas[400];
    __shared__ float Rm[NJOINT][9];
    __shared__ float joints[NJOINT][3];
    __shared__ float Gm[NJOINT][12];

    for (int i = tid; i < 400; i += 64) {
        float v = (i < 300) ? ldf(shape_p, b*300 + i, f32)
                            : ldf(expr_p, b*100 + i - 300, f32);
        betas[i] = v;
        Act[b*KTOT + i] = __float2bfloat16(v);
    }
    if (tid >= 36 && tid < 48) Act[b*KTOT + 400 + tid] = __float2bfloat16(0.f);
    __syncthreads();

    if (tid < 60) {
        int o = tid % 15, q = tid / 15;
        int j = o / 3, kk = o - 3*j;
        const float* js = &JS[j*1200 + kk*400 + q*100];
        float s = 0.f;
        for (int l = 0; l < 100; ++l) s += js[l] * betas[q*100 + l];
        s += __shfl_down(s, 15);
        s += __shfl_down(s, 30);
        if (q == 0) joints[j][kk] = s + baseJ[o];
    }
    if (tid < NJOINT) {
        int j = tid;
        float r[3];
        for (int c = 0; c < 3; ++c) {
            if (j == 0)      r[c] = ldf(grot, b*3 + c, f32);
            else if (j == 1) r[c] = ldf(neck, b*3 + c, f32);
            else if (j == 2) r[c] = ldf(jaw,  b*3 + c, f32);
            else if (j == 3) r[c] = ldf(eye,  b*6 + c, f32);
            else             r[c] = ldf(eye,  b*6 + 3 + c, f32);
        }
        float a0 = r[0] + 1e-8f, a1 = r[1] + 1e-8f, a2 = r[2] + 1e-8f;
        float angle = sqrtf(a0*a0 + a1*a1 + a2*a2);
        float inv = 1.0f / angle;
        float rx = r[0]*inv, ry = r[1]*inv, rz = r[2]*inv;
        float s = sinf(angle), c = cosf(angle);
        float K[9] = {0.f, -rz, ry,  rz, 0.f, -rx,  -ry, rx, 0.f};
        float K2[9];
        for (int rr = 0; rr < 3; ++rr)
            for (int cc = 0; cc < 3; ++cc) {
                float t = 0.f;
                for (int m = 0; m < 3; ++m) t += K[rr*3+m] * K[m*3+cc];
                K2[rr*3+cc] = t;
            }
        for (int i2 = 0; i2 < 9; ++i2) {
            float id = (i2 == 0 || i2 == 4 || i2 == 8) ? 1.f : 0.f;
            Rm[j][i2] = id + s*K[i2] + (1.f - c)*K2[i2];
        }
    }
    __syncthreads();

    if (tid < 36) {
        int i = tid / 9 + 1, rc = tid - (tid/9)*9;
        float id = (rc == 0 || rc == 4 || rc == 8) ? 1.f : 0.f;
        Act[b*KTOT + 400 + tid] = __float2bfloat16(Rm[i][rc] - id);
    }
    if (tid == 0) {
        for (int rr = 0; rr < 3; ++rr) {
            for (int cc = 0; cc < 3; ++cc) Gm[0][rr*4+cc] = Rm[0][rr*3+cc];
            Gm[0][rr*4+3] = joints[0][rr];
        }
        const int par[NJOINT] = {-1, 0, 1, 1, 1};
        for (int j = 1; j < NJOINT; ++j) {
            int p = par[j];
            float rel[3];
            for (int c2 = 0; c2 < 3; ++c2) rel[c2] = joints[j][c2] - joints[p][c2];
            for (int rr = 0; rr < 3; ++rr) {
                for (int cc = 0; cc < 3; ++cc) {
                    float t = 0.f;
                    for (int m = 0; m < 3; ++m) t += Gm[p][rr*4+m] * Rm[j][m*3+cc];
                    Gm[j][rr*4+cc] = t;
                }
                float t = Gm[p][rr*4+3];
                for (int m = 0; m < 3; ++m) t += Gm[p][rr*4+m] * rel[m];
                Gm[j][rr*4+3] = t;
            }
        }
    }
    __syncthreads();

    if (tid < 60) {
        int j = tid / 12, e = tid - j*12, rr = e / 4, cc = e - rr*4;
        float val = Gm[j][e];
        if (cc == 3)
            for (int m = 0; m < 3; ++m) val -= Gm[j][rr*4+m] * joints[j][m];
        Amat[b*60 + tid] = val;
    }

    float part = 0.f;
    for (int i = tid; i < 400; i += 64) part += betas[i]*betas[i];
    part *= 0.001f;
    if (tid == 0) {
        float nn = 0.f, jj = 0.f;
        for (int c = 0; c < 3; ++c) {
            float nv = ldf(neck, b*3+c, f32);
            float jv = ldf(jaw,  b*3+c, f32);
            nn += nv*nv; jj += jv*jv;
        }
        part += 100.f*nn + 0.001f*jj;
    }
    for (int off = 32; off; off >>= 1) part += __shfl_down(part, off);
    if (tid == 0) atomicAdd(reg, part);
}

// Fused GEMM + LBS, B panel persisted in LDS in MFMA-fragment order:
// frag(s,t,fr,quad) at ((s*3+t)*64 + fr*4 + quad)*16B -> each (s,t) read is a
// contiguous 1KB/wave ds_read_b128 (conflict-free). K-loop: 4 global A-loads
// + 3 ds_reads + 12 MFMA per step, no barriers.
__global__ __launch_bounds__(256, 2) void k_gemm_lbs_big(
        const __hip_bfloat16* __restrict__ Act,
        const __hip_bfloat16* __restrict__ Wb,
        const void* __restrict__ v_template,
        const float* __restrict__ Amat,
        const void* __restrict__ weights,
        const void* __restrict__ transl,
        const int* __restrict__ flags,
        void* __restrict__ out) {
    __shared__ __align__(16) __hip_bfloat16 Bsh[NFRAG * 8];   // 43 KB
    __shared__ float tile[64 * LDP];                          // 13.3 KB
    __shared__ float Al[64 * 60];                             // 15.4 KB
    __shared__ float wl[16 * NJOINT];

    int f32 = flags[0];
    int tid = threadIdx.x;
    int wave = tid >> 6, lane = tid & 63;
    int fr = lane & 15, quad = lane >> 4;
    int m0 = blockIdx.x * BM;
    int n0 = blockIdx.y * BN;
    int v0 = blockIdx.y * 16;

    if (tid < 80) {
        int v = v0 + tid / NJOINT;
        wl[tid] = (v < NV) ? ldf(weights, v * NJOINT + tid % NJOINT, f32) : 0.f;
    }
    // stage B panel (rows >= N3 are zero-padded in Wb)
    for (int i = tid; i < NFRAG; i += 256) {
        int s = i / 192, r = i - s*192, t = r >> 6, f = r & 63;
        int bfr = f >> 2, bq = f & 3;
        *(short8*)&Bsh[i*8] =
            *(const short8*)(Wb + (long)(n0 + t*16 + bfr)*KTOT + s*32 + bq*8);
    }
    __syncthreads();

    const __hip_bfloat16* arow[4];
#pragma unroll
    for (int sub = 0; sub < 4; ++sub)
        arow[sub] = Act + (long)(m0 + wave*64 + sub*16 + fr) * KTOT;

    floatx4 acc[4][3];
#pragma unroll
    for (int sub = 0; sub < 4; ++sub)
#pragma unroll
        for (int t = 0; t < 3; ++t) acc[sub][t] = (floatx4){0.f,0.f,0.f,0.f};

    int fidx = fr*4 + quad;
#pragma unroll
    for (int s = 0; s < 14; ++s) {
        short8 bb[3];
#pragma unroll
        for (int t = 0; t < 3; ++t)
            bb[t] = *(const short8*)&Bsh[((s*3 + t)*64 + fidx)*8];
#pragma unroll
        for (int sub = 0; sub < 4; ++sub) {
            short8 a = *(const short8*)(arow[sub] + s*32 + quad*8);
#pragma unroll
            for (int t = 0; t < 3; ++t)
                acc[sub][t] = __builtin_amdgcn_mfma_f32_16x16x32_bf16(a, bb[t], acc[sub][t], 0, 0, 0);
        }
    }

    // Epilogue: 4 passes (wave p's 64 rows), cross-wave tile + Al in LDS
    int vloc = tid & 15, mrow = tid >> 4;
    int v = v0 + vloc;
    float tpl0 = 0.f, tpl1 = 0.f, tpl2 = 0.f;
    if (v < NV) {
        tpl0 = ldf(v_template, v*3 + 0, f32);
        tpl1 = ldf(v_template, v*3 + 1, f32);
        tpl2 = ldf(v_template, v*3 + 2, f32);
    }
    for (int p = 0; p < 4; ++p) {
        __syncthreads();
        if (wave == p) {
#pragma unroll
            for (int sub = 0; sub < 4; ++sub)
#pragma unroll
                for (int t = 0; t < 3; ++t)
#pragma unroll
                    for (int rr = 0; rr < 4; ++rr)
                        tile[(sub*16 + quad*4 + rr)*LDP + t*16 + fr] = acc[sub][t][rr];
        }
        for (int i = tid; i < 64 * 60; i += 256) Al[i] = Amat[(m0 + p*64)*60 + i];
        __syncthreads();
        if (v >= NV) continue;
        float w0 = wl[vloc*NJOINT+0], w1 = wl[vloc*NJOINT+1], w2 = wl[vloc*NJOINT+2];
        float w3 = wl[vloc*NJOINT+3], w4 = wl[vloc*NJOINT+4];
#pragma unroll
        for (int it = 0; it < 4; ++it) {
            int mloc = mrow + 16*it;
            int m = m0 + p*64 + mloc;
            float p0 = tile[mloc*LDP + vloc*3 + 0] + tpl0;
            float p1 = tile[mloc*LDP + vloc*3 + 1] + tpl1;
            float p2 = tile[mloc*LDP + vloc*3 + 2] + tpl2;
            const float* A = &Al[mloc*60];
#pragma unroll
            for (int c = 0; c < 3; ++c) {
                float t0 = w0*A[c*4+0] + w1*A[12+c*4+0] + w2*A[24+c*4+0] + w3*A[36+c*4+0] + w4*A[48+c*4+0];
                float t1 = w0*A[c*4+1] + w1*A[12+c*4+1] + w2*A[24+c*4+1] + w3*A[36+c*4+1] + w4*A[48+c*4+1];
                float t2 = w0*A[c*4+2] + w1*A[12+c*4+2] + w2*A[24+c*4+2] + w3*A[36+c*4+2] + w4*A[48+c*4+2];
                float t3 = w0*A[c*4+3] + w1*A[12+c*4+3] + w2*A[24+c*4+3] + w3*A[36+c*4+3] + w4*A[48+c*4+3];
                float val = t0*p0 + t1*p1 + t2*p2 + t3 + ldf(transl, m*3 + c, f32);
                stf_nt(out, ((long)m*NV + v)*3 + c, val, f32);
            }
        }
    }
}

// Fallback (small ws): register-direct from raw inputs (round-5 structure).
__global__ __launch_bounds__(256) void k_gemm_lbs_small(
        const __hip_bfloat16* __restrict__ Act,
        const void* __restrict__ shapedirs,
        const void* __restrict__ posedirs,
        const void* __restrict__ v_template,
        const float* __restrict__ Amat,
        const void* __restrict__ weights,
        const void* __restrict__ transl,
        const int* __restrict__ flags,
        void* __restrict__ out) {
    __shared__ float tile[64 * LDP];
    __shared__ float Al[64 * 60];
    __shared__ float wl[16 * NJOINT];
    __shared__ __align__(16) __hip_bfloat16 Bs2[BN * 64];

    int f32 = flags[0];
    int tid = threadIdx.x;
    int wave = tid >> 6, lane = tid & 63;
    int fr = lane & 15, quad = lane >> 4;
    int m0 = blockIdx.x * BM;
    int n0 = blockIdx.y * BN;
    int v0 = blockIdx.y * 16;

    if (tid < 80) {
        int v = v0 + tid / NJOINT;
        wl[tid] = (v < NV) ? ldf(weights, v * NJOINT + tid % NJOINT, f32) : 0.f;
    }
    for (int i = tid; i < BN * 64; i += 256) {
        int n = i >> 6, kk = i & 63;
        int nc = min(n0 + n, N3 - 1);
        float val = 0.f;
        if (kk < 16)      val = ldf(shapedirs, (long)nc*KBETA + 384 + kk, f32);
        else if (kk < 52) val = ldf(posedirs, (long)(kk-16)*N3 + nc, f32);
        Bs2[n*64 + kk] = __float2bfloat16(val);
    }
    __syncthreads();

    const float* arow4 = nullptr; (void)arow4;
    const __hip_bfloat16* arow[4];
#pragma unroll
    for (int sub = 0; sub < 4; ++sub)
        arow[sub] = Act + (long)(m0 + wave*64 + sub*16 + fr) * KTOT;
    int nr[3];
#pragma unroll
    for (int t = 0; t < 3; ++t) nr[t] = min(n0 + t*16 + fr, N3 - 1);

    floatx4 acc[4][3];
#pragma unroll
    for (int sub = 0; sub < 4; ++sub)
#pragma unroll
        for (int t = 0; t < 3; ++t) acc[sub][t] = (floatx4){0.f,0.f,0.f,0.f};

#pragma unroll
    for (int s = 0; s < 14; ++s) {
        short8 bb[3];
#pragma unroll
        for (int t = 0; t < 3; ++t) {
            if (s < 12) bb[t] = ld8bf(shapedirs, (long)nr[t]*KBETA + s*32 + quad*8, f32);
            else        bb[t] = *(short8*)&Bs2[(t*16 + fr)*64 + (s-12)*32 + quad*8];
        }
#pragma unroll
        for (int sub = 0; sub < 4; ++sub) {
            short8 a = *(const short8*)(arow[sub] + s*32 + quad*8);
#pragma unroll
            for (int t = 0; t < 3; ++t)
                acc[sub][t] = __builtin_amdgcn_mfma_f32_16x16x32_bf16(a, bb[t], acc[sub][t], 0, 0, 0);
        }
    }

    int vloc = tid & 15, mrow = tid >> 4;
    int v = v0 + vloc;
    float tpl0 = 0.f, tpl1 = 0.f, tpl2 = 0.f;
    if (v < NV) {
        tpl0 = ldf(v_template, v*3 + 0, f32);
        tpl1 = ldf(v_template, v*3 + 1, f32);
        tpl2 = ldf(v_template, v*3 + 2, f32);
    }
    for (int p = 0; p < 4; ++p) {
        __syncthreads();
        if (wave == p) {
#pragma unroll
            for (int sub = 0; sub < 4; ++sub)
#pragma unroll
                for (int t = 0; t < 3; ++t)
#pragma unroll
                    for (int rr = 0; rr < 4; ++rr)
                        tile[(sub*16 + quad*4 + rr)*LDP + t*16 + fr] = acc[sub][t][rr];
        }
        for (int i = tid; i < 64 * 60; i += 256) Al[i] = Amat[(m0 + p*64)*60 + i];
        __syncthreads();
        if (v >= NV) continue;
        float w0 = wl[vloc*NJOINT+0], w1 = wl[vloc*NJOINT+1], w2 = wl[vloc*NJOINT+2];
        float w3 = wl[vloc*NJOINT+3], w4 = wl[vloc*NJOINT+4];
#pragma unroll
        for (int it = 0; it < 4; ++it) {
            int mloc = mrow + 16*it;
            int m = m0 + p*64 + mloc;
            float p0 = tile[mloc*LDP + vloc*3 + 0] + tpl0;
            float p1 = tile[mloc*LDP + vloc*3 + 1] + tpl1;
            float p2 = tile[mloc*LDP + vloc*3 + 2] + tpl2;
            const float* A = &Al[mloc*60];
#pragma unroll
            for (int c = 0; c < 3; ++c) {
                float t0 = w0*A[c*4+0] + w1*A[12+c*4+0] + w2*A[24+c*4+0] + w3*A[36+c*4+0] + w4*A[48+c*4+0];
                float t1 = w0*A[c*4+1] + w1*A[12+c*4+1] + w2*A[24+c*4+1] + w3*A[36+c*4+1] + w4*A[48+c*4+1];
                float t2 = w0*A[c*4+2] + w1*A[12+c*4+2] + w2*A[24+c*4+2] + w3*A[36+c*4+2] + w4*A[48+c*4+2];
                float t3 = w0*A[c*4+3] + w1*A[12+c*4+3] + w2*A[24+c*4+3] + w3*A[36+c*4+3] + w4*A[48+c*4+3];
                float val = t0*p0 + t1*p1 + t2*p2 + t3 + ldf(transl, m*3 + c, f32);
                stf(out, ((long)m*NV + v)*3 + c, val, f32);
            }
        }
    }
}

__global__ __launch_bounds__(64) void k_lmk(const void* __restrict__ verts,
                                            const void* __restrict__ bary,
                                            const int* __restrict__ faces,
                                            const void* __restrict__ lmk_idx,
                                            const void* __restrict__ transl,
                                            const float* __restrict__ reg,
                                            const int* __restrict__ flags,
                                            void* __restrict__ out) {
    int f32 = flags[0], i64 = flags[1];
    int b = blockIdx.x, tid = threadIdx.x;
    if (b == 0 && tid == 63)
        stf(out, (long)BATCH*NV*3 + (long)BATCH*NLMK*3, reg[0], f32);
    if (tid >= NLMK) return;
    int f = i64 ? (int)((const long long*)lmk_idx)[tid]
                : ((const int*)lmk_idx)[tid];
    float acc[3] = {0.f, 0.f, 0.f};
    float bsum = 0.f;
    for (int fi = 0; fi < 3; ++fi) {
        int vi = faces[f*3 + fi];
        float bc = ldf(bary, tid*3 + fi, f32);
        bsum += bc;
#pragma unroll
        for (int c = 0; c < 3; ++c)
            acc[c] += bc * ldf(verts, ((long)b*NV + vi)*3 + c, f32);
    }
#pragma unroll
    for (int c = 0; c < 3; ++c) {
        float val = acc[c] + (1.f - bsum) * ldf(transl, b*3 + c, f32);
        stf(out, (long)BATCH*NV*3 + ((long)b*NLMK + tid)*3 + c, val, f32);
    }
}

extern "C" void kernel_launch(void* const* d_in, const int* in_sizes, int n_in,
                              void* d_out, int out_size, void* d_ws, size_t ws_size,
                              hipStream_t stream) {
    const void* shape_p   = d_in[0];
    const void* expr_p    = d_in[1];
    const void* grot      = d_in[2];
    const void* neck      = d_in[3];
    const void* jaw       = d_in[4];
    const void* eye       = d_in[5];
    const void* transl    = d_in[6];
    const void* v_templ   = d_in[7];
    const void* shapedirs = d_in[8];
    const void* posedirs  = d_in[9];
    const void* Jreg      = d_in[10];
    const void* weights   = d_in[11];
    const void* bary      = d_in[12];
    const int*  faces     = (const int*)d_in[14];
    const void* lmk_idx   = d_in[15];

    char* ws = (char*)d_ws;
    float* JS      = (float*)(ws + WS_JS);
    float* baseJ   = (float*)(ws + WS_BASEJ);
    float* reg     = (float*)(ws + WS_REG);
    int*   flags   = (int*)(ws + WS_FLAGS);
    float* Amat    = (float*)(ws + WS_AMAT);
    __hip_bfloat16* Act = (__hip_bfloat16*)(ws + WS_ACT);
    __hip_bfloat16* Wb  = (__hip_bfloat16*)(ws + WS_WB);
    bool big = ws_size >= (size_t)WS_FULL;

    k_init<<<24, 256, 0, stream>>>((float*)ws, shape_p, lmk_idx, flags);
    if (big) k_cvt<<<NPADB, 448, 0, stream>>>(shapedirs, posedirs, flags, Wb);
    k_js<<<dim3(3, 64), 256, 0, stream>>>(Jreg, shapedirs, v_templ, flags, JS, baseJ);
    k_batch<<<BATCH, 64, 0, stream>>>(shape_p, expr_p, grot, neck, jaw, eye,
                                      JS, baseJ, flags, Act, Amat, reg);
    dim3 grid(BATCH/BM, (N3 + BN - 1)/BN);
    if (big)
        k_gemm_lbs_big<<<grid, 256, 0, stream>>>(Act, Wb, v_templ, Amat,
                                                 weights, transl, flags, d_out);
    else
        k_gemm_lbs_small<<<grid, 256, 0, stream>>>(Act, shapedirs, posedirs, v_templ,
                                                   Amat, weights, transl, flags, d_out);
    k_lmk<<<BATCH, 64, 0, stream>>>(d_out, bary, faces, lmk_idx, transl, reg, flags, d_out);
}

// Round 7
// 308.646 us; speedup vs baseline: 1.1368x; 1.1368x over previous
//
#include <hip/hip_runtime.h>
#include <hip/hip_bf16.h>

#define BATCH 1024
#define NV 5023
#define NJOINT 5
#define NLMK 51
#define N3 (NV*3)        // 15069
#define NPADB 15072      // N3 padded to multiple of 48
#define KBETA 400
#define KTOT 448         // 400 betas + 36 pose_feature + 12 zero pad

#define BM 256           // batches per block (4 waves x 64 rows)
#define BN 48            // output cols per block = 16 vertices
#define NVC 128          // v-chunks for k_js_part

typedef __attribute__((ext_vector_type(8))) short short8;
typedef __attribute__((ext_vector_type(4))) float floatx4;

// ---------------- workspace byte offsets ----------------
#define WS_JS      0          // 6000 f32
#define WS_BASEJ   24064      // 15 f32
#define WS_REG     24512      // 1 f32
#define WS_FLAGS   24520      // 2 ints
#define WS_AMAT    24576      // 1024*60 f32   -> ends 270336
#define WS_ACT     270336     // 1024*448 bf16 -> ends 1187840
#define WS_WB      1187840    // 15072*448 bf16 -> ends 14692352
#define WS_FULL    14692352

__device__ __forceinline__ float ldf(const void* p, long i, int f32) {
    if (f32) return ((const float*)p)[i];
    return __bfloat162float(((const __hip_bfloat16*)p)[i]);
}
__device__ __forceinline__ short8 ld8bf(const void* p, long i, int f32) {
    if (f32) {
        const float* q = (const float*)p + i;
        short8 r;
#pragma unroll
        for (int j = 0; j < 8; ++j) {
            __hip_bfloat16 h = __float2bfloat16(q[j]);
            r[j] = *reinterpret_cast<short*>(&h);
        }
        return r;
    }
    return *(const short8*)((const __hip_bfloat16*)p + i);
}
__device__ __forceinline__ void stf(void* p, long i, float v, int f32) {
    if (f32) ((float*)p)[i] = v;
    else ((__hip_bfloat16*)p)[i] = __float2bfloat16(v);
}

// zero JS/baseJ/reg (fallback path needs JS zeroed; big path needs only reg) + dtype probe
__global__ void k_init(float* ws0, const void* shape_p, const void* lmk_idx, int* flags) {
    int i = blockIdx.x * 256 + threadIdx.x;
    if (i < 6129) ws0[i] = 0.f;
    if (blockIdx.x == 0) {
        __shared__ float mx[64];
        int tid = threadIdx.x;
        if (tid < 64) {
            unsigned short h = ((const unsigned short*)shape_p)[2 * tid];
            union { unsigned short u; __hip_bfloat16 b; } cv; cv.u = h;
            float v = fabsf(__bfloat162float(cv.b));
            if (v != v) v = 3.4e38f;
            mx[tid] = v;
        }
        __syncthreads();
        if (tid == 0) {
            float m = 0.f;
            for (int j = 0; j < 64; ++j) m = fmaxf(m, mx[j]);
            flags[0] = (m > 1e4f) ? 1 : 0;
            int i64 = 1;
            const int* q = (const int*)lmk_idx;
            for (int j = 0; j < 25; ++j) if (q[2*j+1] != 0) i64 = 0;
            flags[1] = i64;
        }
    }
}

// Pack B panel bf16, vectorized 8-wide: Wb[n][k].
// grid: NPADB*56/256 = 3297 blocks. frag g -> (n = g/56, k = (g%56)*8).
__global__ __launch_bounds__(256) void k_cvt(const void* __restrict__ shapedirs,
                                             const void* __restrict__ posedirs,
                                             const int* __restrict__ flags,
                                             __hip_bfloat16* __restrict__ Wb) {
    int f32 = flags[0];
    int g = blockIdx.x * 256 + threadIdx.x;
    int n = g / 56, kg = g - n * 56;
    int k = kg * 8;
    short8 o;
#pragma unroll
    for (int e = 0; e < 8; ++e) o[e] = 0;
    if (n < N3) {
        if (kg < 50) {
            o = ld8bf(shapedirs, (long)n * KBETA + k, f32);
        } else if (kg < 55) {
#pragma unroll
            for (int e = 0; e < 8; ++e) {
                int kk = k + e - 400;
                float val = (kk < 36) ? ldf(posedirs, (long)kk * N3 + n, f32) : 0.f;
                __hip_bfloat16 h = __float2bfloat16(val);
                o[e] = *reinterpret_cast<short*>(&h);
            }
        }
    }
    *(short8*)(Wb + (long)n * KTOT + k) = o;
}

// Phase 1: per-(k, v-chunk) partial sums, no atomics. PART lives in d_out scratch.
// PART[((k*NVC+vc)*5 + j)*401 + l]
__global__ __launch_bounds__(256) void k_js_part(const void* __restrict__ Jreg,
                                                 const __hip_bfloat16* __restrict__ Wb,
                                                 const void* __restrict__ v_template,
                                                 const int* __restrict__ flags,
                                                 float* __restrict__ PART) {
    int f32 = flags[0];
    int k = blockIdx.x;        // 0..2
    int vc = blockIdx.y;       // 0..NVC-1
    int tid = threadIdx.x;     // 0..255
    int v0 = vc * 40, v1 = min(NV, v0 + 40);
    int l2 = tid + 256;        // 400 == template col
    float acc1[NJOINT] = {0,0,0,0,0};
    float acc2[NJOINT] = {0,0,0,0,0};
    for (int v = v0; v < v1; ++v) {
        float s1 = __bfloat162float(Wb[(long)(v*3 + k)*KTOT + tid]);
        float s2 = 0.f;
        if (l2 < 400)       s2 = __bfloat162float(Wb[(long)(v*3 + k)*KTOT + l2]);
        else if (l2 == 400) s2 = ldf(v_template, v*3 + k, f32);
#pragma unroll
        for (int j = 0; j < NJOINT; ++j) {
            float jr = ldf(Jreg, j*NV + v, f32);
            acc1[j] += jr * s1;
            acc2[j] += jr * s2;
        }
    }
    long base = ((long)(k*NVC + vc)*5)*401;
#pragma unroll
    for (int j = 0; j < NJOINT; ++j) {
        PART[base + j*401 + tid] = acc1[j];
        if (l2 <= 400) PART[base + j*401 + l2] = acc2[j];
    }
}

// Phase 2: reduce over NVC chunks -> JS / baseJ.
__global__ __launch_bounds__(256) void k_js_red(const float* __restrict__ PART,
                                                float* __restrict__ JS,
                                                float* __restrict__ baseJ) {
    int o = blockIdx.x * 256 + threadIdx.x;
    if (o >= 3*5*401) return;
    int k = o / 2005, r = o - k*2005;
    int j = r / 401, l = r - j*401;
    float s = 0.f;
    long base = ((long)(k*NVC)*5 + j)*401 + l;
    for (int vc = 0; vc < NVC; ++vc) s += PART[base + (long)vc*2005];
    if (l < 400) JS[j*1200 + k*400 + l] = s;
    else         baseJ[j*3 + k] = s;
}

// Fallback JS (atomic, from raw shapedirs) for small ws.
__global__ void k_js_atomic(const void* __restrict__ Jreg,
                            const void* __restrict__ shapedirs,
                            const void* __restrict__ v_template,
                            const int* __restrict__ flags,
                            float* __restrict__ JS, float* __restrict__ baseJ) {
    int f32 = flags[0];
    int k = blockIdx.x, vc = blockIdx.y, tid = threadIdx.x;
    int v0 = vc * 79, v1 = min(NV, v0 + 79);
    int l2 = tid + 256;
    float acc1[NJOINT] = {0,0,0,0,0};
    float acc2[NJOINT] = {0,0,0,0,0};
    for (int v = v0; v < v1; ++v) {
        float s1 = ldf(shapedirs, (long)v*1200 + k*400 + tid, f32);
        float s2 = 0.f;
        if (l2 < 400)       s2 = ldf(shapedirs, (long)v*1200 + k*400 + l2, f32);
        else if (l2 == 400) s2 = ldf(v_template, v*3 + k, f32);
#pragma unroll
        for (int j = 0; j < NJOINT; ++j) {
            float jr = ldf(Jreg, j*NV + v, f32);
            acc1[j] += jr * s1;
            acc2[j] += jr * s2;
        }
    }
#pragma unroll
    for (int j = 0; j < NJOINT; ++j) {
        atomicAdd(&JS[j*1200 + k*400 + tid], acc1[j]);
        if (l2 < 400)       atomicAdd(&JS[j*1200 + k*400 + l2], acc2[j]);
        else if (l2 == 400) atomicAdd(&baseJ[j*3 + k], acc2[j]);
    }
}

// Per-batch: betas->Act(bf16), joints, rodrigues, chain, A matrices, reg
__global__ __launch_bounds__(64) void k_batch(
        const void* __restrict__ shape_p, const void* __restrict__ expr_p,
        const void* __restrict__ grot, const void* __restrict__ neck,
        const void* __restrict__ jaw,  const void* __restrict__ eye,
        const float* __restrict__ JS, const float* __restrict__ baseJ,
        const int* __restrict__ flags,
        __hip_bfloat16* __restrict__ Act, float* __restrict__ Amat, float* __restrict__ reg) {
    int f32 = flags[0];
    int b = blockIdx.x, tid = threadIdx.x;
    __shared__ float betas[400];
    __shared__ float Rm[NJOINT][9];
    __shared__ float joints[NJOINT][3];
    __shared__ float Gm[NJOINT][12];

    for (int i = tid; i < 400; i += 64) {
        float v = (i < 300) ? ldf(shape_p, b*300 + i, f32)
                            : ldf(expr_p, b*100 + i - 300, f32);
        betas[i] = v;
        Act[b*KTOT + i] = __float2bfloat16(v);
    }
    if (tid >= 36 && tid < 48) Act[b*KTOT + 400 + tid] = __float2bfloat16(0.f);
    __syncthreads();

    if (tid < 60) {
        int o = tid % 15, q = tid / 15;
        int j = o / 3, kk = o - 3*j;
        const float* js = &JS[j*1200 + kk*400 + q*100];
        float s = 0.f;
        for (int l = 0; l < 100; ++l) s += js[l] * betas[q*100 + l];
        s += __shfl_down(s, 15);
        s += __shfl_down(s, 30);
        if (q == 0) joints[j][kk] = s + baseJ[o];
    }
    if (tid < NJOINT) {
        int j = tid;
        float r[3];
        for (int c = 0; c < 3; ++c) {
            if (j == 0)      r[c] = ldf(grot, b*3 + c, f32);
            else if (j == 1) r[c] = ldf(neck, b*3 + c, f32);
            else if (j == 2) r[c] = ldf(jaw,  b*3 + c, f32);
            else if (j == 3) r[c] = ldf(eye,  b*6 + c, f32);
            else             r[c] = ldf(eye,  b*6 + 3 + c, f32);
        }
        float a0 = r[0] + 1e-8f, a1 = r[1] + 1e-8f, a2 = r[2] + 1e-8f;
        float angle = sqrtf(a0*a0 + a1*a1 + a2*a2);
        float inv = 1.0f / angle;
        float rx = r[0]*inv, ry = r[1]*inv, rz = r[2]*inv;
        float s = sinf(angle), c = cosf(angle);
        float K[9] = {0.f, -rz, ry,  rz, 0.f, -rx,  -ry, rx, 0.f};
        float K2[9];
        for (int rr = 0; rr < 3; ++rr)
            for (int cc = 0; cc < 3; ++cc) {
                float t = 0.f;
                for (int m = 0; m < 3; ++m) t += K[rr*3+m] * K[m*3+cc];
                K2[rr*3+cc] = t;
            }
        for (int i2 = 0; i2 < 9; ++i2) {
            float id = (i2 == 0 || i2 == 4 || i2 == 8) ? 1.f : 0.f;
            Rm[j][i2] = id + s*K[i2] + (1.f - c)*K2[i2];
        }
    }
    __syncthreads();

    if (tid < 36) {
        int i = tid / 9 + 1, rc = tid - (tid/9)*9;
        float id = (rc == 0 || rc == 4 || rc == 8) ? 1.f : 0.f;
        Act[b*KTOT + 400 + tid] = __float2bfloat16(Rm[i][rc] - id);
    }
    if (tid == 0) {
        for (int rr = 0; rr < 3; ++rr) {
            for (int cc = 0; cc < 3; ++cc) Gm[0][rr*4+cc] = Rm[0][rr*3+cc];
            Gm[0][rr*4+3] = joints[0][rr];
        }
        const int par[NJOINT] = {-1, 0, 1, 1, 1};
        for (int j = 1; j < NJOINT; ++j) {
            int p = par[j];
            float rel[3];
            for (int c2 = 0; c2 < 3; ++c2) rel[c2] = joints[j][c2] - joints[p][c2];
            for (int rr = 0; rr < 3; ++rr) {
                for (int cc = 0; cc < 3; ++cc) {
                    float t = 0.f;
                    for (int m = 0; m < 3; ++m) t += Gm[p][rr*4+m] * Rm[j][m*3+cc];
                    Gm[j][rr*4+cc] = t;
                }
                float t = Gm[p][rr*4+3];
                for (int m = 0; m < 3; ++m) t += Gm[p][rr*4+m] * rel[m];
                Gm[j][rr*4+3] = t;
            }
        }
    }
    __syncthreads();

    if (tid < 60) {
        int j = tid / 12, e = tid - j*12, rr = e / 4, cc = e - rr*4;
        float val = Gm[j][e];
        if (cc == 3)
            for (int m = 0; m < 3; ++m) val -= Gm[j][rr*4+m] * joints[j][m];
        Amat[b*60 + tid] = val;
    }

    float part = 0.f;
    for (int i = tid; i < 400; i += 64) part += betas[i]*betas[i];
    part *= 0.001f;
    if (tid == 0) {
        float nn = 0.f, jj = 0.f;
        for (int c = 0; c < 3; ++c) {
            float nv = ldf(neck, b*3+c, f32);
            float jv = ldf(jaw,  b*3+c, f32);
            nn += nv*nv; jj += jv*jv;
        }
        part += 100.f*nn + 0.001f*jj;
    }
    for (int off = 32; off; off >>= 1) part += __shfl_down(part, off);
    if (tid == 0) atomicAdd(reg, part);
}

// ------- GEMM helpers: depth-2 software-pipelined fragments -------
__device__ __forceinline__ void ld_frags(const __hip_bfloat16* abase,
                                         const __hip_bfloat16* bbase,
                                         int s, short8* A, short8* B) {
#pragma unroll
    for (int q = 0; q < 4; ++q)
        A[q] = *(const short8*)(abase + (long)q*16*KTOT + s*32);
#pragma unroll
    for (int t = 0; t < 3; ++t)
        B[t] = *(const short8*)(bbase + (long)t*16*KTOT + s*32);
}
__device__ __forceinline__ void do_mfma(floatx4 acc[4][3], const short8* A, const short8* B) {
#pragma unroll
    for (int q = 0; q < 4; ++q)
#pragma unroll
        for (int t = 0; t < 3; ++t)
            acc[q][t] = __builtin_amdgcn_mfma_f32_16x16x32_bf16(A[q], B[t], acc[q][t], 0, 0, 0);
}

// Fused GEMM + LBS: register-direct A/B, explicit depth-2 pipeline, no K-loop
// barriers; per-wave-private epilogue tiles; normal (cached) stores.
__global__ __launch_bounds__(256) void k_gemm_lbs_big(
        const __hip_bfloat16* __restrict__ Act,
        const __hip_bfloat16* __restrict__ Wb,
        const void* __restrict__ v_template,
        const float* __restrict__ Amat,
        const void* __restrict__ weights,
        const void* __restrict__ transl,
        const int* __restrict__ flags,
        void* __restrict__ out) {
    __shared__ float tileS[4][16*49 + 4];   // per-wave 16x48 acc tile (12.7 KB)
    __shared__ float AlS[4][960];           // per-wave 16x60 A rows (15.4 KB)
    __shared__ float wl[80];
    __shared__ float tl[BM*3];              // transl rows (3 KB)

    int f32 = flags[0];
    int tid = threadIdx.x;
    int wave = tid >> 6, lane = tid & 63;
    int fr = lane & 15, quad = lane >> 4;
    int m0 = blockIdx.x * BM;               // 4 m-blocks, fastest-varying
    int n0 = blockIdx.y * BN;               // 314 n-blocks
    int v0 = blockIdx.y * 16;

    if (tid < 80) {
        int v = v0 + tid / 5;
        wl[tid] = (v < NV) ? ldf(weights, v*5 + tid % 5, f32) : 0.f;
    }
    for (int i = tid; i < BM*3; i += 256) tl[i] = ldf(transl, (long)m0*3 + i, f32);

    const __hip_bfloat16* abase = Act + (long)(m0 + wave*64 + fr) * KTOT + quad*8;
    const __hip_bfloat16* bbase = Wb  + (long)(n0 + fr) * KTOT + quad*8;

    floatx4 acc[4][3];
#pragma unroll
    for (int q = 0; q < 4; ++q)
#pragma unroll
        for (int t = 0; t < 3; ++t) acc[q][t] = (floatx4){0.f,0.f,0.f,0.f};

    short8 A0[4], B0[3], A1[4], B1[3];
    ld_frags(abase, bbase, 0, A0, B0);
#pragma unroll
    for (int s = 0; s < 14; s += 2) {
        ld_frags(abase, bbase, s+1, A1, B1);
        do_mfma(acc, A0, B0);
        if (s + 2 < 14) ld_frags(abase, bbase, s+2, A0, B0);
        do_mfma(acc, A1, B1);
    }

    // Epilogue: 4 sub-passes, wave-private tile/Al regions.
    int vloc = fr, rgrp = quad;
    int v = v0 + vloc;
    float tpl0 = 0.f, tpl1 = 0.f, tpl2 = 0.f;
    if (v < NV) {
        tpl0 = ldf(v_template, v*3 + 0, f32);
        tpl1 = ldf(v_template, v*3 + 1, f32);
        tpl2 = ldf(v_template, v*3 + 2, f32);
    }
    float w0 = wl[vloc*5+0], w1 = wl[vloc*5+1], w2 = wl[vloc*5+2];
    float w3 = wl[vloc*5+3], w4 = wl[vloc*5+4];

    for (int sub = 0; sub < 4; ++sub) {
#pragma unroll
        for (int t = 0; t < 3; ++t)
#pragma unroll
            for (int rr = 0; rr < 4; ++rr)
                tileS[wave][(quad*4 + rr)*49 + t*16 + fr] = acc[sub][t][rr];
        for (int i = lane; i < 960; i += 64)
            AlS[wave][i] = Amat[(long)(m0 + wave*64 + sub*16)*60 + i];
        __syncthreads();
        if (v < NV) {
#pragma unroll
            for (int rr = 0; rr < 4; ++rr) {
                int mloc = rgrp*4 + rr;
                int mg = wave*64 + sub*16 + mloc;
                long m = m0 + mg;
                float p0 = tileS[wave][mloc*49 + vloc*3 + 0] + tpl0;
                float p1 = tileS[wave][mloc*49 + vloc*3 + 1] + tpl1;
                float p2 = tileS[wave][mloc*49 + vloc*3 + 2] + tpl2;
                const float* A = &AlS[wave][mloc*60];
#pragma unroll
                for (int c = 0; c < 3; ++c) {
                    float t0 = w0*A[c*4+0] + w1*A[12+c*4+0] + w2*A[24+c*4+0] + w3*A[36+c*4+0] + w4*A[48+c*4+0];
                    float t1 = w0*A[c*4+1] + w1*A[12+c*4+1] + w2*A[24+c*4+1] + w3*A[36+c*4+1] + w4*A[48+c*4+1];
                    float t2 = w0*A[c*4+2] + w1*A[12+c*4+2] + w2*A[24+c*4+2] + w3*A[36+c*4+2] + w4*A[48+c*4+2];
                    float t3 = w0*A[c*4+3] + w1*A[12+c*4+3] + w2*A[24+c*4+3] + w3*A[36+c*4+3] + w4*A[48+c*4+3];
                    float val = t0*p0 + t1*p1 + t2*p2 + t3 + tl[mg*3 + c];
                    stf(out, (m*NV + v)*3 + c, val, f32);
                }
            }
        }
        __syncthreads();
    }
}

// Fallback (small ws): register-direct from raw inputs.
__global__ __launch_bounds__(256) void k_gemm_lbs_small(
        const __hip_bfloat16* __restrict__ Act,
        const void* __restrict__ shapedirs,
        const void* __restrict__ posedirs,
        const void* __restrict__ v_template,
        const float* __restrict__ Amat,
        const void* __restrict__ weights,
        const void* __restrict__ transl,
        const int* __restrict__ flags,
        void* __restrict__ out) {
    __shared__ float tileS[4][16*49 + 4];
    __shared__ float AlS[4][960];
    __shared__ float wl[80];
    __shared__ __align__(16) __hip_bfloat16 Bs2[BN * 64];

    int f32 = flags[0];
    int tid = threadIdx.x;
    int wave = tid >> 6, lane = tid & 63;
    int fr = lane & 15, quad = lane >> 4;
    int m0 = blockIdx.x * BM;
    int n0 = blockIdx.y * BN;
    int v0 = blockIdx.y * 16;

    if (tid < 80) {
        int v = v0 + tid / 5;
        wl[tid] = (v < NV) ? ldf(weights, v*5 + tid % 5, f32) : 0.f;
    }
    for (int i = tid; i < BN * 64; i += 256) {
        int n = i >> 6, kk = i & 63;
        int nc = min(n0 + n, N3 - 1);
        float val = 0.f;
        if (kk < 16)      val = ldf(shapedirs, (long)nc*KBETA + 384 + kk, f32);
        else if (kk < 52) val = ldf(posedirs, (long)(kk-16)*N3 + nc, f32);
        Bs2[n*64 + kk] = __float2bfloat16(val);
    }
    __syncthreads();

    const __hip_bfloat16* arow[4];
#pragma unroll
    for (int sub = 0; sub < 4; ++sub)
        arow[sub] = Act + (long)(m0 + wave*64 + sub*16 + fr) * KTOT;
    int nr[3];
#pragma unroll
    for (int t = 0; t < 3; ++t) nr[t] = min(n0 + t*16 + fr, N3 - 1);

    floatx4 acc[4][3];
#pragma unroll
    for (int sub = 0; sub < 4; ++sub)
#pragma unroll
        for (int t = 0; t < 3; ++t) acc[sub][t] = (floatx4){0.f,0.f,0.f,0.f};

#pragma unroll
    for (int s = 0; s < 14; ++s) {
        short8 bb[3];
#pragma unroll
        for (int t = 0; t < 3; ++t) {
            if (s < 12) bb[t] = ld8bf(shapedirs, (long)nr[t]*KBETA + s*32 + quad*8, f32);
            else        bb[t] = *(short8*)&Bs2[(t*16 + fr)*64 + (s-12)*32 + quad*8];
        }
#pragma unroll
        for (int sub = 0; sub < 4; ++sub) {
            short8 a = *(const short8*)(arow[sub] + s*32 + quad*8);
#pragma unroll
            for (int t = 0; t < 3; ++t)
                acc[sub][t] = __builtin_amdgcn_mfma_f32_16x16x32_bf16(a, bb[t], acc[sub][t], 0, 0, 0);
        }
    }

    int vloc = fr, rgrp = quad;
    int v = v0 + vloc;
    float tpl0 = 0.f, tpl1 = 0.f, tpl2 = 0.f;
    if (v < NV) {
        tpl0 = ldf(v_template, v*3 + 0, f32);
        tpl1 = ldf(v_template, v*3 + 1, f32);
        tpl2 = ldf(v_template, v*3 + 2, f32);
    }
    float w0 = wl[vloc*5+0], w1 = wl[vloc*5+1], w2 = wl[vloc*5+2];
    float w3 = wl[vloc*5+3], w4 = wl[vloc*5+4];
    for (int sub = 0; sub < 4; ++sub) {
#pragma unroll
        for (int t = 0; t < 3; ++t)
#pragma unroll
            for (int rr = 0; rr < 4; ++rr)
                tileS[wave][(quad*4 + rr)*49 + t*16 + fr] = acc[sub][t][rr];
        for (int i = lane; i < 960; i += 64)
            AlS[wave][i] = Amat[(long)(m0 + wave*64 + sub*16)*60 + i];
        __syncthreads();
        if (v < NV) {
#pragma unroll
            for (int rr = 0; rr < 4; ++rr) {
                int mloc = rgrp*4 + rr;
                long m = m0 + wave*64 + sub*16 + mloc;
                float p0 = tileS[wave][mloc*49 + vloc*3 + 0] + tpl0;
                float p1 = tileS[wave][mloc*49 + vloc*3 + 1] + tpl1;
                float p2 = tileS[wave][mloc*49 + vloc*3 + 2] + tpl2;
                const float* A = &AlS[wave][mloc*60];
#pragma unroll
                for (int c = 0; c < 3; ++c) {
                    float t0 = w0*A[c*4+0] + w1*A[12+c*4+0] + w2*A[24+c*4+0] + w3*A[36+c*4+0] + w4*A[48+c*4+0];
                    float t1 = w0*A[c*4+1] + w1*A[12+c*4+1] + w2*A[24+c*4+1] + w3*A[36+c*4+1] + w4*A[48+c*4+1];
                    float t2 = w0*A[c*4+2] + w1*A[12+c*4+2] + w2*A[24+c*4+2] + w3*A[36+c*4+2] + w4*A[48+c*4+2];
                    float t3 = w0*A[c*4+3] + w1*A[12+c*4+3] + w2*A[24+c*4+3] + w3*A[36+c*4+3] + w4*A[48+c*4+3];
                    float val = t0*p0 + t1*p1 + t2*p2 + t3 + ldf(transl, m*3 + c, f32);
                    stf(out, (m*NV + v)*3 + c, val, f32);
                }
            }
        }
        __syncthreads();
    }
}

__global__ __launch_bounds__(64) void k_lmk(const void* __restrict__ verts,
                                            const void* __restrict__ bary,
                                            const int* __restrict__ faces,
                                            const void* __restrict__ lmk_idx,
                                            const void* __restrict__ transl,
                                            const float* __restrict__ reg,
                                            const int* __restrict__ flags,
                                            void* __restrict__ out) {
    int f32 = flags[0], i64 = flags[1];
    int b = blockIdx.x, tid = threadIdx.x;
    if (b == 0 && tid == 63)
        stf(out, (long)BATCH*NV*3 + (long)BATCH*NLMK*3, reg[0], f32);
    if (tid >= NLMK) return;
    int f = i64 ? (int)((const long long*)lmk_idx)[tid]
                : ((const int*)lmk_idx)[tid];
    float acc[3] = {0.f, 0.f, 0.f};
    float bsum = 0.f;
    for (int fi = 0; fi < 3; ++fi) {
        int vi = faces[f*3 + fi];
        float bc = ldf(bary, tid*3 + fi, f32);
        bsum += bc;
#pragma unroll
        for (int c = 0; c < 3; ++c)
            acc[c] += bc * ldf(verts, ((long)b*NV + vi)*3 + c, f32);
    }
#pragma unroll
    for (int c = 0; c < 3; ++c) {
        float val = acc[c] + (1.f - bsum) * ldf(transl, b*3 + c, f32);
        stf(out, (long)BATCH*NV*3 + ((long)b*NLMK + tid)*3 + c, val, f32);
    }
}

extern "C" void kernel_launch(void* const* d_in, const int* in_sizes, int n_in,
                              void* d_out, int out_size, void* d_ws, size_t ws_size,
                              hipStream_t stream) {
    const void* shape_p   = d_in[0];
    const void* expr_p    = d_in[1];
    const void* grot      = d_in[2];
    const void* neck      = d_in[3];
    const void* jaw       = d_in[4];
    const void* eye       = d_in[5];
    const void* transl    = d_in[6];
    const void* v_templ   = d_in[7];
    const void* shapedirs = d_in[8];
    const void* posedirs  = d_in[9];
    const void* Jreg      = d_in[10];
    const void* weights   = d_in[11];
    const void* bary      = d_in[12];
    const int*  faces     = (const int*)d_in[14];
    const void* lmk_idx   = d_in[15];

    char* ws = (char*)d_ws;
    float* JS      = (float*)(ws + WS_JS);
    float* baseJ   = (float*)(ws + WS_BASEJ);
    float* reg     = (float*)(ws + WS_REG);
    int*   flags   = (int*)(ws + WS_FLAGS);
    float* Amat    = (float*)(ws + WS_AMAT);
    __hip_bfloat16* Act = (__hip_bfloat16*)(ws + WS_ACT);
    __hip_bfloat16* Wb  = (__hip_bfloat16*)(ws + WS_WB);
    float* PART    = (float*)d_out;   // scratch before verts are written
    bool big = ws_size >= (size_t)WS_FULL;

    k_init<<<24, 256, 0, stream>>>((float*)ws, shape_p, lmk_idx, flags);
    if (big) {
        k_cvt<<<NPADB*56/256, 256, 0, stream>>>(shapedirs, posedirs, flags, Wb);
        k_js_part<<<dim3(3, NVC), 256, 0, stream>>>(Jreg, Wb, v_templ, flags, PART);
        k_js_red<<<24, 256, 0, stream>>>(PART, JS, baseJ);
    } else {
        k_js_atomic<<<dim3(3, 64), 256, 0, stream>>>(Jreg, shapedirs, v_templ, flags, JS, baseJ);
    }
    k_batch<<<BATCH, 64, 0, stream>>>(shape_p, expr_p, grot, neck, jaw, eye,
                                      JS, baseJ, flags, Act, Amat, reg);
    dim3 grid(BATCH/BM, (N3 + BN - 1)/BN);
    if (big)
        k_gemm_lbs_big<<<grid, 256, 0, stream>>>(Act, Wb, v_templ, Amat,
                                                 weights, transl, flags, d_out);
    else
        k_gemm_lbs_small<<<grid, 256, 0, stream>>>(Act, shapedirs, posedirs, v_templ,
                                                   Amat, weights, transl, flags, d_out);
    k_lmk<<<BATCH, 64, 0, stream>>>(d_out, bary, faces, lmk_idx, transl, reg, flags, d_out);
}

// Round 8
// 294.012 us; speedup vs baseline: 1.1934x; 1.0498x over previous
//
#include <hip/hip_runtime.h>
#include <hip/hip_bf16.h>

#define BATCH 1024
#define NV 5023
#define NJOINT 5
#define NLMK 51
#define N3 (NV*3)        // 15069
#define NPADB 15072      // N3 padded to multiple of 48
#define KBETA 400
#define KTOT 448         // 400 betas + 36 pose_feature + 12 zero pad

#define BM 64            // batches per block
#define BN 48            // output cols per block = 16 vertices
#define NVC 128          // v-chunks for k_js_part

typedef __attribute__((ext_vector_type(8))) short short8;
typedef __attribute__((ext_vector_type(4))) float floatx4;
typedef __attribute__((ext_vector_type(4))) float float4v;

// ---------------- workspace byte offsets ----------------
#define WS_JS      0          // 6000 f32
#define WS_BASEJ   24064      // 15 f32
#define WS_REG     24512      // 1 f32
#define WS_FLAGS   24520      // 2 ints (fallback path only)
#define WS_AMAT    24576      // 1024*60 f32   -> ends 270336
#define WS_ACT     270336     // 1024*448 bf16 -> ends 1187840
#define WS_WB      1187840    // 15072*448 bf16 -> ends 14692352
#define WS_FULL    14692352

__device__ __forceinline__ float ldf(const void* p, long i, int f32) {
    if (f32) return ((const float*)p)[i];
    return __bfloat162float(((const __hip_bfloat16*)p)[i]);
}
__device__ __forceinline__ short8 ld8bf(const void* p, long i, int f32) {
    if (f32) {
        const float* q = (const float*)p + i;
        short8 r;
#pragma unroll
        for (int j = 0; j < 8; ++j) {
            __hip_bfloat16 h = __float2bfloat16(q[j]);
            r[j] = *reinterpret_cast<short*>(&h);
        }
        return r;
    }
    return *(const short8*)((const __hip_bfloat16*)p + i);
}
__device__ __forceinline__ void stf(void* p, long i, float v, int f32) {
    if (f32) ((float*)p)[i] = v;
    else ((__hip_bfloat16*)p)[i] = __float2bfloat16(v);
}

// per-wave inline dtype probe: f32 data read as bf16 halfwords blows past 1e4
__device__ __forceinline__ int probe_f32(const void* shape_p) {
    int lane = threadIdx.x & 63;
    unsigned short h = ((const unsigned short*)shape_p)[2 * lane];
    union { unsigned short u; __hip_bfloat16 b; } cv; cv.u = h;
    float v = fabsf(__bfloat162float(cv.b));
    if (v != v) v = 3.4e38f;
#pragma unroll
    for (int off = 32; off; off >>= 1) v = fmaxf(v, __shfl_down(v, off));
    v = __shfl(v, 0);
    return v > 1e4f;
}
__device__ __forceinline__ int probe_i64(const void* lmk_idx) {
    int lane = threadIdx.x & 63;
    const int* q = (const int*)lmk_idx;
    int odd_nonzero = (lane < 25) && (q[2*lane + 1] != 0);
    unsigned long long b = __ballot(odd_nonzero);
    return b == 0ull;
}

// fallback-path init: zero JS/baseJ/reg + write flags
__global__ void k_init(float* ws0, const void* shape_p, const void* lmk_idx, int* flags) {
    int i = blockIdx.x * 256 + threadIdx.x;
    if (i < 6129) ws0[i] = 0.f;
    if (blockIdx.x == 0 && threadIdx.x < 64) {
        int f = probe_f32(shape_p);
        int i64 = probe_i64(lmk_idx);
        if (threadIdx.x == 0) { flags[0] = f; flags[1] = i64; }
    }
}

// Pack B panel bf16, vectorized: Wb[n][k]. Also zeroes reg (block 0).
__global__ __launch_bounds__(256) void k_cvt(const void* __restrict__ shapedirs,
                                             const void* __restrict__ posedirs,
                                             const void* __restrict__ shape_p,
                                             float* __restrict__ reg,
                                             __hip_bfloat16* __restrict__ Wb) {
    int f32 = probe_f32(shape_p);
    if (blockIdx.x == 0 && threadIdx.x == 0) reg[0] = 0.f;
    int g = blockIdx.x * 256 + threadIdx.x;
    int n = g / 56, kg = g - n * 56;
    int k = kg * 8;
    short8 o;
#pragma unroll
    for (int e = 0; e < 8; ++e) o[e] = 0;
    if (n < N3) {
        if (kg < 50) {
            o = ld8bf(shapedirs, (long)n * KBETA + k, f32);
        } else if (kg < 55) {
#pragma unroll
            for (int e = 0; e < 8; ++e) {
                int kk = k + e - 400;
                float val = (kk < 36) ? ldf(posedirs, (long)kk * N3 + n, f32) : 0.f;
                __hip_bfloat16 h = __float2bfloat16(val);
                o[e] = *reinterpret_cast<short*>(&h);
            }
        }
    }
    *(short8*)(Wb + (long)n * KTOT + k) = o;
}

// Phase 1: per-(k, v-chunk) partial sums -> PART (d_out scratch), no atomics.
__global__ __launch_bounds__(256) void k_js_part(const void* __restrict__ Jreg,
                                                 const __hip_bfloat16* __restrict__ Wb,
                                                 const void* __restrict__ v_template,
                                                 const void* __restrict__ shape_p,
                                                 float* __restrict__ PART) {
    int f32 = probe_f32(shape_p);
    int k = blockIdx.x;        // 0..2
    int vc = blockIdx.y;       // 0..NVC-1
    int tid = threadIdx.x;
    int v0 = vc * 40, v1 = min(NV, v0 + 40);
    int l2 = tid + 256;        // 400 == template col
    float acc1[NJOINT] = {0,0,0,0,0};
    float acc2[NJOINT] = {0,0,0,0,0};
    for (int v = v0; v < v1; ++v) {
        float s1 = __bfloat162float(Wb[(long)(v*3 + k)*KTOT + tid]);
        float s2 = 0.f;
        if (l2 < 400)       s2 = __bfloat162float(Wb[(long)(v*3 + k)*KTOT + l2]);
        else if (l2 == 400) s2 = ldf(v_template, v*3 + k, f32);
#pragma unroll
        for (int j = 0; j < NJOINT; ++j) {
            float jr = ldf(Jreg, j*NV + v, f32);
            acc1[j] += jr * s1;
            acc2[j] += jr * s2;
        }
    }
    long base = ((long)(k*NVC + vc)*5)*401;
#pragma unroll
    for (int j = 0; j < NJOINT; ++j) {
        PART[base + j*401 + tid] = acc1[j];
        if (l2 <= 400) PART[base + j*401 + l2] = acc2[j];
    }
}

// Phase 2: reduce over NVC chunks -> JS / baseJ.
__global__ __launch_bounds__(256) void k_js_red(const float* __restrict__ PART,
                                                float* __restrict__ JS,
                                                float* __restrict__ baseJ) {
    int o = blockIdx.x * 256 + threadIdx.x;
    if (o >= 3*5*401) return;
    int k = o / 2005, r = o - k*2005;
    int j = r / 401, l = r - j*401;
    float s = 0.f;
    long base = ((long)(k*NVC)*5 + j)*401 + l;
    for (int vc = 0; vc < NVC; ++vc) s += PART[base + (long)vc*2005];
    if (l < 400) JS[j*1200 + k*400 + l] = s;
    else         baseJ[j*3 + k] = s;
}

// Fallback JS (atomic, raw shapedirs) for small ws.
__global__ void k_js_atomic(const void* __restrict__ Jreg,
                            const void* __restrict__ shapedirs,
                            const void* __restrict__ v_template,
                            const int* __restrict__ flags,
                            float* __restrict__ JS, float* __restrict__ baseJ) {
    int f32 = flags[0];
    int k = blockIdx.x, vc = blockIdx.y, tid = threadIdx.x;
    int v0 = vc * 79, v1 = min(NV, v0 + 79);
    int l2 = tid + 256;
    float acc1[NJOINT] = {0,0,0,0,0};
    float acc2[NJOINT] = {0,0,0,0,0};
    for (int v = v0; v < v1; ++v) {
        float s1 = ldf(shapedirs, (long)v*1200 + k*400 + tid, f32);
        float s2 = 0.f;
        if (l2 < 400)       s2 = ldf(shapedirs, (long)v*1200 + k*400 + l2, f32);
        else if (l2 == 400) s2 = ldf(v_template, v*3 + k, f32);
#pragma unroll
        for (int j = 0; j < NJOINT; ++j) {
            float jr = ldf(Jreg, j*NV + v, f32);
            acc1[j] += jr * s1;
            acc2[j] += jr * s2;
        }
    }
#pragma unroll
    for (int j = 0; j < NJOINT; ++j) {
        atomicAdd(&JS[j*1200 + k*400 + tid], acc1[j]);
        if (l2 < 400)       atomicAdd(&JS[j*1200 + k*400 + l2], acc2[j]);
        else if (l2 == 400) atomicAdd(&baseJ[j*3 + k], acc2[j]);
    }
}

// Per-batch: betas->Act(bf16), joints, rodrigues, chain, A matrices, reg
__global__ __launch_bounds__(64) void k_batch(
        const void* __restrict__ shape_p, const void* __restrict__ expr_p,
        const void* __restrict__ grot, const void* __restrict__ neck,
        const void* __restrict__ jaw,  const void* __restrict__ eye,
        const float* __restrict__ JS, const float* __restrict__ baseJ,
        __hip_bfloat16* __restrict__ Act, float* __restrict__ Amat, float* __restrict__ reg) {
    int f32 = probe_f32(shape_p);
    int b = blockIdx.x, tid = threadIdx.x;
    __shared__ float betas[400];
    __shared__ float Rm[NJOINT][9];
    __shared__ float joints[NJOINT][3];
    __shared__ float Gm[NJOINT][12];

    for (int i = tid; i < 400; i += 64) {
        float v = (i < 300) ? ldf(shape_p, b*300 + i, f32)
                            : ldf(expr_p, b*100 + i - 300, f32);
        betas[i] = v;
        Act[b*KTOT + i] = __float2bfloat16(v);
    }
    if (tid >= 36 && tid < 48) Act[b*KTOT + 400 + tid] = __float2bfloat16(0.f);
    __syncthreads();

    if (tid < 60) {
        int o = tid % 15, q = tid / 15;
        int j = o / 3, kk = o - 3*j;
        const float* js = &JS[j*1200 + kk*400 + q*100];
        float s = 0.f;
        for (int l = 0; l < 100; ++l) s += js[l] * betas[q*100 + l];
        s += __shfl_down(s, 15);
        s += __shfl_down(s, 30);
        if (q == 0) joints[j][kk] = s + baseJ[o];
    }
    if (tid < NJOINT) {
        int j = tid;
        float r[3];
        for (int c = 0; c < 3; ++c) {
            if (j == 0)      r[c] = ldf(grot, b*3 + c, f32);
            else if (j == 1) r[c] = ldf(neck, b*3 + c, f32);
            else if (j == 2) r[c] = ldf(jaw,  b*3 + c, f32);
            else if (j == 3) r[c] = ldf(eye,  b*6 + c, f32);
            else             r[c] = ldf(eye,  b*6 + 3 + c, f32);
        }
        float a0 = r[0] + 1e-8f, a1 = r[1] + 1e-8f, a2 = r[2] + 1e-8f;
        float angle = sqrtf(a0*a0 + a1*a1 + a2*a2);
        float inv = 1.0f / angle;
        float rx = r[0]*inv, ry = r[1]*inv, rz = r[2]*inv;
        float s = sinf(angle), c = cosf(angle);
        float K[9] = {0.f, -rz, ry,  rz, 0.f, -rx,  -ry, rx, 0.f};
        float K2[9];
        for (int rr = 0; rr < 3; ++rr)
            for (int cc = 0; cc < 3; ++cc) {
                float t = 0.f;
                for (int m = 0; m < 3; ++m) t += K[rr*3+m] * K[m*3+cc];
                K2[rr*3+cc] = t;
            }
        for (int i2 = 0; i2 < 9; ++i2) {
            float id = (i2 == 0 || i2 == 4 || i2 == 8) ? 1.f : 0.f;
            Rm[j][i2] = id + s*K[i2] + (1.f - c)*K2[i2];
        }
    }
    __syncthreads();

    if (tid < 36) {
        int i = tid / 9 + 1, rc = tid - (tid/9)*9;
        float id = (rc == 0 || rc == 4 || rc == 8) ? 1.f : 0.f;
        Act[b*KTOT + 400 + tid] = __float2bfloat16(Rm[i][rc] - id);
    }
    if (tid == 0) {
        for (int rr = 0; rr < 3; ++rr) {
            for (int cc = 0; cc < 3; ++cc) Gm[0][rr*4+cc] = Rm[0][rr*3+cc];
            Gm[0][rr*4+3] = joints[0][rr];
        }
        const int par[NJOINT] = {-1, 0, 1, 1, 1};
        for (int j = 1; j < NJOINT; ++j) {
            int p = par[j];
            float rel[3];
            for (int c2 = 0; c2 < 3; ++c2) rel[c2] = joints[j][c2] - joints[p][c2];
            for (int rr = 0; rr < 3; ++rr) {
                for (int cc = 0; cc < 3; ++cc) {
                    float t = 0.f;
                    for (int m = 0; m < 3; ++m) t += Gm[p][rr*4+m] * Rm[j][m*3+cc];
                    Gm[j][rr*4+cc] = t;
                }
                float t = Gm[p][rr*4+3];
                for (int m = 0; m < 3; ++m) t += Gm[p][rr*4+m] * rel[m];
                Gm[j][rr*4+3] = t;
            }
        }
    }
    __syncthreads();

    if (tid < 60) {
        int j = tid / 12, e = tid - j*12, rr = e / 4, cc = e - rr*4;
        float val = Gm[j][e];
        if (cc == 3)
            for (int m = 0; m < 3; ++m) val -= Gm[j][rr*4+m] * joints[j][m];
        Amat[b*60 + tid] = val;
    }

    float part = 0.f;
    for (int i = tid; i < 400; i += 64) part += betas[i]*betas[i];
    part *= 0.001f;
    if (tid == 0) {
        float nn = 0.f, jj = 0.f;
        for (int c = 0; c < 3; ++c) {
            float nv = ldf(neck, b*3+c, f32);
            float jv = ldf(jaw,  b*3+c, f32);
            nn += nv*nv; jj += jv*jv;
        }
        part += 100.f*nn + 0.001f*jj;
    }
    for (int off = 32; off; off >>= 1) part += __shfl_down(part, off);
    if (tid == 0) atomicAdd(reg, part);
}

// Fused GEMM + LBS, K split across the 4 waves (steps 4/4/3/3): each wave
// issues all its ~28 independent global loads flat, then MFMAs. Two-stage
// LDS reduction (waves 2,3 add into waves 0,1's tiles), then LBS epilogue
// with m-row-contiguous coalesced stores.
__global__ __launch_bounds__(256, 2) void k_gemm_lbs_big(
        const __hip_bfloat16* __restrict__ Act,
        const __hip_bfloat16* __restrict__ Wb,
        const void* __restrict__ v_template,
        const float* __restrict__ Amat,
        const void* __restrict__ weights,
        const void* __restrict__ transl,
        const void* __restrict__ shape_p,
        void* __restrict__ out) {
    __shared__ float tile[2][BM * 49];   // 25.1 KB
    __shared__ float Al[BM * 60];        // 15.4 KB
    __shared__ float wl[80];
    __shared__ float tl[BM * 3];
    __shared__ float vtl[48];

    int f32 = probe_f32(shape_p);
    int tid = threadIdx.x;
    int wave = tid >> 6, lane = tid & 63;
    int fr = lane & 15, quad = lane >> 4;
    int m0 = blockIdx.x * BM;            // 16 m-blocks, fastest-varying
    int n0 = blockIdx.y * BN;            // 314 n-blocks
    int v0 = blockIdx.y * 16;

    // stage epilogue data (independent of K-loop)
    for (int i = tid; i < BM*60/4; i += 256)
        ((float4v*)Al)[i] = ((const float4v*)(Amat + (long)m0*60))[i];
    if (tid < 80) {
        int v = v0 + tid / 5;
        wl[tid] = (v < NV) ? ldf(weights, v*5 + tid % 5, f32) : 0.f;
    }
    if (tid >= 128 && tid < 128 + BM*3) {
        int i = tid - 128;
        tl[i] = ldf(transl, (long)m0*3 + i, f32);
    }
    if (tid >= 64 && tid < 112) {
        int i = tid - 64;
        vtl[i] = (v0*3 + i < N3) ? ldf(v_template, (long)v0*3 + i, f32) : 0.f;
    }

    // K-chunk for this wave: starts 0,4,8,11; counts 4,4,3,3
    int s0 = wave*4 - (wave > 2 ? 1 : 0);
    int cnt = (wave < 2) ? 4 : 3;
    const __hip_bfloat16* abase = Act + (long)(m0 + fr)*KTOT + quad*8;
    const __hip_bfloat16* bbase = Wb  + (long)(n0 + fr)*KTOT + quad*8;

    short8 Af[4][4], Bf[4][3];
#pragma unroll
    for (int i = 0; i < 4; ++i) {
        if (i < cnt) {
            int s = s0 + i;
#pragma unroll
            for (int q = 0; q < 4; ++q)
                Af[i][q] = *(const short8*)(abase + (long)q*16*KTOT + s*32);
#pragma unroll
            for (int t = 0; t < 3; ++t)
                Bf[i][t] = *(const short8*)(bbase + (long)t*16*KTOT + s*32);
        }
    }

    floatx4 acc[4][3];
#pragma unroll
    for (int q = 0; q < 4; ++q)
#pragma unroll
        for (int t = 0; t < 3; ++t) acc[q][t] = (floatx4){0.f,0.f,0.f,0.f};

#pragma unroll
    for (int i = 0; i < 4; ++i) {
        if (i < cnt) {
#pragma unroll
            for (int q = 0; q < 4; ++q)
#pragma unroll
                for (int t = 0; t < 3; ++t)
                    acc[q][t] = __builtin_amdgcn_mfma_f32_16x16x32_bf16(Af[i][q], Bf[i][t], acc[q][t], 0, 0, 0);
        }
    }

    // two-stage reduction: waves 0,1 write; waves 2,3 add
    if (wave < 2) {
#pragma unroll
        for (int q = 0; q < 4; ++q)
#pragma unroll
            for (int t = 0; t < 3; ++t)
#pragma unroll
                for (int rr = 0; rr < 4; ++rr)
                    tile[wave][(q*16 + quad*4 + rr)*49 + t*16 + fr] = acc[q][t][rr];
    }
    __syncthreads();
    if (wave >= 2) {
        float* tw = tile[wave - 2];
#pragma unroll
        for (int q = 0; q < 4; ++q)
#pragma unroll
            for (int t = 0; t < 3; ++t)
#pragma unroll
                for (int rr = 0; rr < 4; ++rr)
                    tw[(q*16 + quad*4 + rr)*49 + t*16 + fr] += acc[q][t][rr];
    }
    __syncthreads();

    // LBS epilogue: thread = (m-row, quarter of 16 verts); stores 12
    // consecutive f32 -> 4-lane-contiguous 192 B runs per m-row.
    int m = tid >> 2, idx = tid & 3;
    const float* A = &Al[m*60];
    long obase = ((long)(m0 + m)*NV + v0)*3;
#pragma unroll
    for (int vi = 0; vi < 4; ++vi) {
        int vloc = idx*4 + vi;
        int v = v0 + vloc;
        if (v >= NV) break;
        float p0 = tile[0][m*49 + vloc*3 + 0] + tile[1][m*49 + vloc*3 + 0] + vtl[vloc*3 + 0];
        float p1 = tile[0][m*49 + vloc*3 + 1] + tile[1][m*49 + vloc*3 + 1] + vtl[vloc*3 + 1];
        float p2 = tile[0][m*49 + vloc*3 + 2] + tile[1][m*49 + vloc*3 + 2] + vtl[vloc*3 + 2];
        float w0 = wl[vloc*5+0], w1 = wl[vloc*5+1], w2 = wl[vloc*5+2];
        float w3 = wl[vloc*5+3], w4 = wl[vloc*5+4];
#pragma unroll
        for (int c = 0; c < 3; ++c) {
            float t0 = w0*A[c*4+0] + w1*A[12+c*4+0] + w2*A[24+c*4+0] + w3*A[36+c*4+0] + w4*A[48+c*4+0];
            float t1 = w0*A[c*4+1] + w1*A[12+c*4+1] + w2*A[24+c*4+1] + w3*A[36+c*4+1] + w4*A[48+c*4+1];
            float t2 = w0*A[c*4+2] + w1*A[12+c*4+2] + w2*A[24+c*4+2] + w3*A[36+c*4+2] + w4*A[48+c*4+2];
            float t3 = w0*A[c*4+3] + w1*A[12+c*4+3] + w2*A[24+c*4+3] + w3*A[36+c*4+3] + w4*A[48+c*4+3];
            float val = t0*p0 + t1*p1 + t2*p2 + t3 + tl[m*3 + c];
            stf(out, obase + vloc*3 + c, val, f32);
        }
    }
}

// Fallback (small ws): register-direct from raw inputs (round-7 structure).
__global__ __launch_bounds__(256) void k_gemm_lbs_small(
        const __hip_bfloat16* __restrict__ Act,
        const void* __restrict__ shapedirs,
        const void* __restrict__ posedirs,
        const void* __restrict__ v_template,
        const float* __restrict__ Amat,
        const void* __restrict__ weights,
        const void* __restrict__ transl,
        const int* __restrict__ flags,
        void* __restrict__ out) {
    __shared__ float tileS[4][16*49 + 4];
    __shared__ float AlS[4][960];
    __shared__ float wl[80];
    __shared__ __align__(16) __hip_bfloat16 Bs2[BN * 64];

    int f32 = flags[0];
    int tid = threadIdx.x;
    int wave = tid >> 6, lane = tid & 63;
    int fr = lane & 15, quad = lane >> 4;
    int m0 = blockIdx.x * 256;
    int n0 = blockIdx.y * BN;
    int v0 = blockIdx.y * 16;

    if (tid < 80) {
        int v = v0 + tid / 5;
        wl[tid] = (v < NV) ? ldf(weights, v*5 + tid % 5, f32) : 0.f;
    }
    for (int i = tid; i < BN * 64; i += 256) {
        int n = i >> 6, kk = i & 63;
        int nc = min(n0 + n, N3 - 1);
        float val = 0.f;
        if (kk < 16)      val = ldf(shapedirs, (long)nc*KBETA + 384 + kk, f32);
        else if (kk < 52) val = ldf(posedirs, (long)(kk-16)*N3 + nc, f32);
        Bs2[n*64 + kk] = __float2bfloat16(val);
    }
    __syncthreads();

    const __hip_bfloat16* arow[4];
#pragma unroll
    for (int sub = 0; sub < 4; ++sub)
        arow[sub] = Act + (long)(m0 + wave*64 + sub*16 + fr) * KTOT;
    int nr[3];
#pragma unroll
    for (int t = 0; t < 3; ++t) nr[t] = min(n0 + t*16 + fr, N3 - 1);

    floatx4 acc[4][3];
#pragma unroll
    for (int sub = 0; sub < 4; ++sub)
#pragma unroll
        for (int t = 0; t < 3; ++t) acc[sub][t] = (floatx4){0.f,0.f,0.f,0.f};

#pragma unroll
    for (int s = 0; s < 14; ++s) {
        short8 bb[3];
#pragma unroll
        for (int t = 0; t < 3; ++t) {
            if (s < 12) bb[t] = ld8bf(shapedirs, (long)nr[t]*KBETA + s*32 + quad*8, f32);
            else        bb[t] = *(short8*)&Bs2[(t*16 + fr)*64 + (s-12)*32 + quad*8];
        }
#pragma unroll
        for (int sub = 0; sub < 4; ++sub) {
            short8 a = *(const short8*)(arow[sub] + s*32 + quad*8);
#pragma unroll
            for (int t = 0; t < 3; ++t)
                acc[sub][t] = __builtin_amdgcn_mfma_f32_16x16x32_bf16(a, bb[t], acc[sub][t], 0, 0, 0);
        }
    }

    int vloc = fr, rgrp = quad;
    int v = v0 + vloc;
    float tpl0 = 0.f, tpl1 = 0.f, tpl2 = 0.f;
    if (v < NV) {
        tpl0 = ldf(v_template, v*3 + 0, f32);
        tpl1 = ldf(v_template, v*3 + 1, f32);
        tpl2 = ldf(v_template, v*3 + 2, f32);
    }
    float w0 = wl[vloc*5+0], w1 = wl[vloc*5+1], w2 = wl[vloc*5+2];
    float w3 = wl[vloc*5+3], w4 = wl[vloc*5+4];
    for (int sub = 0; sub < 4; ++sub) {
#pragma unroll
        for (int t = 0; t < 3; ++t)
#pragma unroll
            for (int rr = 0; rr < 4; ++rr)
                tileS[wave][(quad*4 + rr)*49 + t*16 + fr] = acc[sub][t][rr];
        for (int i = lane; i < 960; i += 64)
            AlS[wave][i] = Amat[(long)(m0 + wave*64 + sub*16)*60 + i];
        __syncthreads();
        if (v < NV) {
#pragma unroll
            for (int rr = 0; rr < 4; ++rr) {
                int mloc = rgrp*4 + rr;
                long m = m0 + wave*64 + sub*16 + mloc;
                float p0 = tileS[wave][mloc*49 + vloc*3 + 0] + tpl0;
                float p1 = tileS[wave][mloc*49 + vloc*3 + 1] + tpl1;
                float p2 = tileS[wave][mloc*49 + vloc*3 + 2] + tpl2;
                const float* A = &AlS[wave][mloc*60];
#pragma unroll
                for (int c = 0; c < 3; ++c) {
                    float t0 = w0*A[c*4+0] + w1*A[12+c*4+0] + w2*A[24+c*4+0] + w3*A[36+c*4+0] + w4*A[48+c*4+0];
                    float t1 = w0*A[c*4+1] + w1*A[12+c*4+1] + w2*A[24+c*4+1] + w3*A[36+c*4+1] + w4*A[48+c*4+1];
                    float t2 = w0*A[c*4+2] + w1*A[12+c*4+2] + w2*A[24+c*4+2] + w3*A[36+c*4+2] + w4*A[48+c*4+2];
                    float t3 = w0*A[c*4+3] + w1*A[12+c*4+3] + w2*A[24+c*4+3] + w3*A[36+c*4+3] + w4*A[48+c*4+3];
                    float val = t0*p0 + t1*p1 + t2*p2 + t3 + ldf(transl, m*3 + c, f32);
                    stf(out, (m*NV + v)*3 + c, val, f32);
                }
            }
        }
        __syncthreads();
    }
}

__global__ __launch_bounds__(64) void k_lmk(const void* __restrict__ verts,
                                            const void* __restrict__ bary,
                                            const int* __restrict__ faces,
                                            const void* __restrict__ lmk_idx,
                                            const void* __restrict__ transl,
                                            const float* __restrict__ reg,
                                            const void* __restrict__ shape_p,
                                            void* __restrict__ out) {
    int f32 = probe_f32(shape_p);
    int i64 = probe_i64(lmk_idx);
    int b = blockIdx.x, tid = threadIdx.x;
    if (b == 0 && tid == 63)
        stf(out, (long)BATCH*NV*3 + (long)BATCH*NLMK*3, reg[0], f32);
    if (tid >= NLMK) return;
    int f = i64 ? (int)((const long long*)lmk_idx)[tid]
                : ((const int*)lmk_idx)[tid];
    float acc[3] = {0.f, 0.f, 0.f};
    float bsum = 0.f;
    for (int fi = 0; fi < 3; ++fi) {
        int vi = faces[f*3 + fi];
        float bc = ldf(bary, tid*3 + fi, f32);
        bsum += bc;
#pragma unroll
        for (int c = 0; c < 3; ++c)
            acc[c] += bc * ldf(verts, ((long)b*NV + vi)*3 + c, f32);
    }
#pragma unroll
    for (int c = 0; c < 3; ++c) {
        float val = acc[c] + (1.f - bsum) * ldf(transl, b*3 + c, f32);
        stf(out, (long)BATCH*NV*3 + ((long)b*NLMK + tid)*3 + c, val, f32);
    }
}

extern "C" void kernel_launch(void* const* d_in, const int* in_sizes, int n_in,
                              void* d_out, int out_size, void* d_ws, size_t ws_size,
                              hipStream_t stream) {
    const void* shape_p   = d_in[0];
    const void* expr_p    = d_in[1];
    const void* grot      = d_in[2];
    const void* neck      = d_in[3];
    const void* jaw       = d_in[4];
    const void* eye       = d_in[5];
    const void* transl    = d_in[6];
    const void* v_templ   = d_in[7];
    const void* shapedirs = d_in[8];
    const void* posedirs  = d_in[9];
    const void* Jreg      = d_in[10];
    const void* weights   = d_in[11];
    const void* bary      = d_in[12];
    const int*  faces     = (const int*)d_in[14];
    const void* lmk_idx   = d_in[15];

    char* ws = (char*)d_ws;
    float* JS      = (float*)(ws + WS_JS);
    float* baseJ   = (float*)(ws + WS_BASEJ);
    float* reg     = (float*)(ws + WS_REG);
    int*   flags   = (int*)(ws + WS_FLAGS);
    float* Amat    = (float*)(ws + WS_AMAT);
    __hip_bfloat16* Act = (__hip_bfloat16*)(ws + WS_ACT);
    __hip_bfloat16* Wb  = (__hip_bfloat16*)(ws + WS_WB);
    float* PART    = (float*)d_out;   // scratch before verts are written
    bool big = ws_size >= (size_t)WS_FULL;

    if (big) {
        k_cvt<<<NPADB*56/256, 256, 0, stream>>>(shapedirs, posedirs, shape_p, reg, Wb);
        k_js_part<<<dim3(3, NVC), 256, 0, stream>>>(Jreg, Wb, v_templ, shape_p, PART);
        k_js_red<<<24, 256, 0, stream>>>(PART, JS, baseJ);
    } else {
        k_init<<<24, 256, 0, stream>>>((float*)ws, shape_p, lmk_idx, flags);
        k_js_atomic<<<dim3(3, 64), 256, 0, stream>>>(Jreg, shapedirs, v_templ, flags, JS, baseJ);
    }
    k_batch<<<BATCH, 64, 0, stream>>>(shape_p, expr_p, grot, neck, jaw, eye,
                                      JS, baseJ, Act, Amat, reg);
    if (big) {
        dim3 grid(BATCH/BM, (N3 + BN - 1)/BN);
        k_gemm_lbs_big<<<grid, 256, 0, stream>>>(Act, Wb, v_templ, Amat,
                                                 weights, transl, shape_p, d_out);
    } else {
        dim3 grid(BATCH/256, (N3 + BN - 1)/BN);
        k_gemm_lbs_small<<<grid, 256, 0, stream>>>(Act, shapedirs, posedirs, v_templ,
                                                   Amat, weights, transl, flags, d_out);
    }
    k_lmk<<<BATCH, 64, 0, stream>>>(d_out, bary, faces, lmk_idx, transl, reg, shape_p, d_out);
}

// Round 9
// 278.696 us; speedup vs baseline: 1.2590x; 1.0550x over previous
//
#include <hip/hip_runtime.h>
#include <hip/hip_bf16.h>

#define BATCH 1024
#define NV 5023
#define NJOINT 5
#define NLMK 51
#define N3 (NV*3)        // 15069
#define NPADB 15072      // N3 padded to multiple of 48
#define KBETA 400
#define KTOT 448         // 400 betas + 36 pose_feature + 12 zero pad

#define BM 64            // batches per block
#define BN 48            // output cols per block = 16 vertices
#define NVC 128          // v-chunks for js_part
#define NPANEL 314       // n-panels
#define CVT_BLKS 3297    // NPADB*56/256

typedef __attribute__((ext_vector_type(8))) short short8;
typedef __attribute__((ext_vector_type(4))) float floatx4;
typedef __attribute__((ext_vector_type(4))) float float4v;

// ---------------- workspace byte offsets ----------------
#define WS_JS      0          // 6000 f32
#define WS_BASEJ   24064      // 15 f32
#define WS_REG     24512      // 1 f32
#define WS_FLAGS   24520      // 2 ints (fallback path only)
#define WS_AMAT    24576      // 1024*60 f32   -> ends 270336
#define WS_ACT     270336     // 1024*448 bf16 -> ends 1187840
#define WS_WB      1187840    // 15072*448 bf16 -> ends 14692352
#define WS_FULL    14692352

__device__ __forceinline__ float ldf(const void* p, long i, int f32) {
    if (f32) return ((const float*)p)[i];
    return __bfloat162float(((const __hip_bfloat16*)p)[i]);
}
__device__ __forceinline__ short8 ld8bf(const void* p, long i, int f32) {
    if (f32) {
        const float* q = (const float*)p + i;
        short8 r;
#pragma unroll
        for (int j = 0; j < 8; ++j) {
            __hip_bfloat16 h = __float2bfloat16(q[j]);
            r[j] = *reinterpret_cast<short*>(&h);
        }
        return r;
    }
    return *(const short8*)((const __hip_bfloat16*)p + i);
}
__device__ __forceinline__ void stf(void* p, long i, float v, int f32) {
    if (f32) ((float*)p)[i] = v;
    else ((__hip_bfloat16*)p)[i] = __float2bfloat16(v);
}

// per-wave inline dtype probe: f32 data read as bf16 halfwords blows past 1e4
__device__ __forceinline__ int probe_f32(const void* shape_p) {
    int lane = threadIdx.x & 63;
    unsigned short h = ((const unsigned short*)shape_p)[2 * lane];
    union { unsigned short u; __hip_bfloat16 b; } cv; cv.u = h;
    float v = fabsf(__bfloat162float(cv.b));
    if (v != v) v = 3.4e38f;
#pragma unroll
    for (int off = 32; off; off >>= 1) v = fmaxf(v, __shfl_down(v, off));
    v = __shfl(v, 0);
    return v > 1e4f;
}
__device__ __forceinline__ int probe_i64(const void* lmk_idx) {
    int lane = threadIdx.x & 63;
    const int* q = (const int*)lmk_idx;
    int odd_nonzero = (lane < 25) && (q[2*lane + 1] != 0);
    unsigned long long b = __ballot(odd_nonzero);
    return b == 0ull;
}

// fallback-path init: zero JS/baseJ/reg + write flags
__global__ void k_init(float* ws0, const void* shape_p, const void* lmk_idx, int* flags) {
    int i = blockIdx.x * 256 + threadIdx.x;
    if (i < 6129) ws0[i] = 0.f;
    if (blockIdx.x == 0 && threadIdx.x < 64) {
        int f = probe_f32(shape_p);
        int i64 = probe_i64(lmk_idx);
        if (threadIdx.x == 0) { flags[0] = f; flags[1] = i64; }
    }
}

// Fused prep (big path): blocks [0,CVT_BLKS) pack Wb; blocks [CVT_BLKS, +384)
// compute js partial sums from RAW shapedirs (independent of Wb -> concurrent).
// Block 0 also zeroes reg.
__global__ __launch_bounds__(256) void k_prep(const void* __restrict__ shapedirs,
                                              const void* __restrict__ posedirs,
                                              const void* __restrict__ Jreg,
                                              const void* __restrict__ v_template,
                                              const void* __restrict__ shape_p,
                                              float* __restrict__ reg,
                                              __hip_bfloat16* __restrict__ Wb,
                                              float* __restrict__ PART) {
    int f32 = probe_f32(shape_p);
    int blk = blockIdx.x, tid = threadIdx.x;
    if (blk < CVT_BLKS) {
        if (blk == 0 && tid == 0) reg[0] = 0.f;
        int g = blk * 256 + tid;
        int n = g / 56, kg = g - n * 56;
        int k = kg * 8;
        short8 o;
#pragma unroll
        for (int e = 0; e < 8; ++e) o[e] = 0;
        if (n < N3) {
            if (kg < 50) {
                o = ld8bf(shapedirs, (long)n * KBETA + k, f32);
            } else if (kg < 55) {
#pragma unroll
                for (int e = 0; e < 8; ++e) {
                    int kk = k + e - 400;
                    float val = (kk < 36) ? ldf(posedirs, (long)kk * N3 + n, f32) : 0.f;
                    __hip_bfloat16 h = __float2bfloat16(val);
                    o[e] = *reinterpret_cast<short*>(&h);
                }
            }
        }
        *(short8*)(Wb + (long)n * KTOT + k) = o;
    } else {
        int b2 = blk - CVT_BLKS;     // 0..383
        int k = b2 >> 7;             // 0..2
        int vc = b2 & 127;           // 0..127
        int v0 = vc * 40, v1 = min(NV, v0 + 40);
        int l2 = tid + 256;          // 400 == template col
        float acc1[NJOINT] = {0,0,0,0,0};
        float acc2[NJOINT] = {0,0,0,0,0};
        for (int v = v0; v < v1; ++v) {
            float s1 = ldf(shapedirs, (long)v*1200 + k*400 + tid, f32);
            float s2 = 0.f;
            if (l2 < 400)       s2 = ldf(shapedirs, (long)v*1200 + k*400 + l2, f32);
            else if (l2 == 400) s2 = ldf(v_template, v*3 + k, f32);
#pragma unroll
            for (int j = 0; j < NJOINT; ++j) {
                float jr = ldf(Jreg, j*NV + v, f32);
                acc1[j] += jr * s1;
                acc2[j] += jr * s2;
            }
        }
        long base = ((long)(k*NVC + vc)*5)*401;
#pragma unroll
        for (int j = 0; j < NJOINT; ++j) {
            PART[base + j*401 + tid] = acc1[j];
            if (l2 <= 400) PART[base + j*401 + l2] = acc2[j];
        }
    }
}

// Reduce over NVC chunks -> JS / baseJ.
__global__ __launch_bounds__(256) void k_js_red(const float* __restrict__ PART,
                                                float* __restrict__ JS,
                                                float* __restrict__ baseJ) {
    int o = blockIdx.x * 256 + threadIdx.x;
    if (o >= 3*5*401) return;
    int k = o / 2005, r = o - k*2005;
    int j = r / 401, l = r - j*401;
    float s = 0.f;
    long base = ((long)(k*NVC)*5 + j)*401 + l;
    for (int vc = 0; vc < NVC; ++vc) s += PART[base + (long)vc*2005];
    if (l < 400) JS[j*1200 + k*400 + l] = s;
    else         baseJ[j*3 + k] = s;
}

// Fallback JS (atomic, raw shapedirs) for small ws.
__global__ void k_js_atomic(const void* __restrict__ Jreg,
                            const void* __restrict__ shapedirs,
                            const void* __restrict__ v_template,
                            const int* __restrict__ flags,
                            float* __restrict__ JS, float* __restrict__ baseJ) {
    int f32 = flags[0];
    int k = blockIdx.x, vc = blockIdx.y, tid = threadIdx.x;
    int v0 = vc * 79, v1 = min(NV, v0 + 79);
    int l2 = tid + 256;
    float acc1[NJOINT] = {0,0,0,0,0};
    float acc2[NJOINT] = {0,0,0,0,0};
    for (int v = v0; v < v1; ++v) {
        float s1 = ldf(shapedirs, (long)v*1200 + k*400 + tid, f32);
        float s2 = 0.f;
        if (l2 < 400)       s2 = ldf(shapedirs, (long)v*1200 + k*400 + l2, f32);
        else if (l2 == 400) s2 = ldf(v_template, v*3 + k, f32);
#pragma unroll
        for (int j = 0; j < NJOINT; ++j) {
            float jr = ldf(Jreg, j*NV + v, f32);
            acc1[j] += jr * s1;
            acc2[j] += jr * s2;
        }
    }
#pragma unroll
    for (int j = 0; j < NJOINT; ++j) {
        atomicAdd(&JS[j*1200 + k*400 + tid], acc1[j]);
        if (l2 < 400)       atomicAdd(&JS[j*1200 + k*400 + l2], acc2[j]);
        else if (l2 == 400) atomicAdd(&baseJ[j*3 + k], acc2[j]);
    }
}

// Per-batch: betas->Act(bf16), joints, rodrigues, chain, A matrices, reg
__global__ __launch_bounds__(64) void k_batch(
        const void* __restrict__ shape_p, const void* __restrict__ expr_p,
        const void* __restrict__ grot, const void* __restrict__ neck,
        const void* __restrict__ jaw,  const void* __restrict__ eye,
        const float* __restrict__ JS, const float* __restrict__ baseJ,
        __hip_bfloat16* __restrict__ Act, float* __restrict__ Amat, float* __restrict__ reg) {
    int f32 = probe_f32(shape_p);
    int b = blockIdx.x, tid = threadIdx.x;
    __shared__ float betas[400];
    __shared__ float Rm[NJOINT][9];
    __shared__ float joints[NJOINT][3];
    __shared__ float Gm[NJOINT][12];

    for (int i = tid; i < 400; i += 64) {
        float v = (i < 300) ? ldf(shape_p, b*300 + i, f32)
                            : ldf(expr_p, b*100 + i - 300, f32);
        betas[i] = v;
        Act[b*KTOT + i] = __float2bfloat16(v);
    }
    if (tid >= 36 && tid < 48) Act[b*KTOT + 400 + tid] = __float2bfloat16(0.f);
    __syncthreads();

    if (tid < 60) {
        int o = tid % 15, q = tid / 15;
        int j = o / 3, kk = o - 3*j;
        const float* js = &JS[j*1200 + kk*400 + q*100];
        float s = 0.f;
        for (int l = 0; l < 100; ++l) s += js[l] * betas[q*100 + l];
        s += __shfl_down(s, 15);
        s += __shfl_down(s, 30);
        if (q == 0) joints[j][kk] = s + baseJ[o];
    }
    if (tid < NJOINT) {
        int j = tid;
        float r[3];
        for (int c = 0; c < 3; ++c) {
            if (j == 0)      r[c] = ldf(grot, b*3 + c, f32);
            else if (j == 1) r[c] = ldf(neck, b*3 + c, f32);
            else if (j == 2) r[c] = ldf(jaw,  b*3 + c, f32);
            else if (j == 3) r[c] = ldf(eye,  b*6 + c, f32);
            else             r[c] = ldf(eye,  b*6 + 3 + c, f32);
        }
        float a0 = r[0] + 1e-8f, a1 = r[1] + 1e-8f, a2 = r[2] + 1e-8f;
        float angle = sqrtf(a0*a0 + a1*a1 + a2*a2);
        float inv = 1.0f / angle;
        float rx = r[0]*inv, ry = r[1]*inv, rz = r[2]*inv;
        float s = sinf(angle), c = cosf(angle);
        float K[9] = {0.f, -rz, ry,  rz, 0.f, -rx,  -ry, rx, 0.f};
        float K2[9];
        for (int rr = 0; rr < 3; ++rr)
            for (int cc = 0; cc < 3; ++cc) {
                float t = 0.f;
                for (int m = 0; m < 3; ++m) t += K[rr*3+m] * K[m*3+cc];
                K2[rr*3+cc] = t;
            }
        for (int i2 = 0; i2 < 9; ++i2) {
            float id = (i2 == 0 || i2 == 4 || i2 == 8) ? 1.f : 0.f;
            Rm[j][i2] = id + s*K[i2] + (1.f - c)*K2[i2];
        }
    }
    __syncthreads();

    if (tid < 36) {
        int i = tid / 9 + 1, rc = tid - (tid/9)*9;
        float id = (rc == 0 || rc == 4 || rc == 8) ? 1.f : 0.f;
        Act[b*KTOT + 400 + tid] = __float2bfloat16(Rm[i][rc] - id);
    }
    if (tid == 0) {
        for (int rr = 0; rr < 3; ++rr) {
            for (int cc = 0; cc < 3; ++cc) Gm[0][rr*4+cc] = Rm[0][rr*3+cc];
            Gm[0][rr*4+3] = joints[0][rr];
        }
        const int par[NJOINT] = {-1, 0, 1, 1, 1};
        for (int j = 1; j < NJOINT; ++j) {
            int p = par[j];
            float rel[3];
            for (int c2 = 0; c2 < 3; ++c2) rel[c2] = joints[j][c2] - joints[p][c2];
            for (int rr = 0; rr < 3; ++rr) {
                for (int cc = 0; cc < 3; ++cc) {
                    float t = 0.f;
                    for (int m = 0; m < 3; ++m) t += Gm[p][rr*4+m] * Rm[j][m*3+cc];
                    Gm[j][rr*4+cc] = t;
                }
                float t = Gm[p][rr*4+3];
                for (int m = 0; m < 3; ++m) t += Gm[p][rr*4+m] * rel[m];
                Gm[j][rr*4+3] = t;
            }
        }
    }
    __syncthreads();

    if (tid < 60) {
        int j = tid / 12, e = tid - j*12, rr = e / 4, cc = e - rr*4;
        float val = Gm[j][e];
        if (cc == 3)
            for (int m = 0; m < 3; ++m) val -= Gm[j][rr*4+m] * joints[j][m];
        Amat[b*60 + tid] = val;
    }

    float part = 0.f;
    for (int i = tid; i < 400; i += 64) part += betas[i]*betas[i];
    part *= 0.001f;
    if (tid == 0) {
        float nn = 0.f, jj = 0.f;
        for (int c = 0; c < 3; ++c) {
            float nv = ldf(neck, b*3+c, f32);
            float jv = ldf(jaw,  b*3+c, f32);
            nn += nv*nv; jj += jv*jv;
        }
        part += 100.f*nn + 0.001f*jj;
    }
    for (int off = 32; off; off >>= 1) part += __shfl_down(part, off);
    if (tid == 0) atomicAdd(reg, part);
}

// Fused GEMM + LBS: 512 threads = 8 waves, K split 2/2/2/2/2/2/1/1 (short
// per-wave chains, loads batch in VGPRs). 4-tile LDS tree reduction.
// XCD-swizzled 1D grid: all 16 m-blocks of one Wb panel -> one XCD's L2.
__global__ __launch_bounds__(512, 4) void k_gemm_lbs_big(
        const __hip_bfloat16* __restrict__ Act,
        const __hip_bfloat16* __restrict__ Wb,
        const void* __restrict__ v_template,
        const float* __restrict__ Amat,
        const void* __restrict__ weights,
        const void* __restrict__ transl,
        const void* __restrict__ shape_p,
        void* __restrict__ out) {
    __shared__ float tile[4][BM * 49];   // 50.2 KB
    __shared__ float Al[BM * 60];        // 15.4 KB
    __shared__ float wl[80];
    __shared__ float tl[BM * 3];
    __shared__ float vtl[48];

    int f32 = probe_f32(shape_p);
    int tid = threadIdx.x;
    int wave = tid >> 6, lane = tid & 63;
    int fr = lane & 15, quad = lane >> 4;

    // swizzle: panel P's 16 m-blocks all map to XCD P%8 (round-robin assumption)
    int lin = blockIdx.x;
    int xcd = lin & 7, slot = lin >> 3;
    int P = (slot >> 4) * 8 + xcd;
    int mblk = slot & 15;
    if (P >= NPANEL) return;
    int m0 = mblk * BM;
    int n0 = P * BN;
    int v0 = P * 16;

    // staging (before K-loop; consumed after barriers)
    for (int i = tid; i < BM*60/4; i += 512)
        ((float4v*)Al)[i] = ((const float4v*)(Amat + (long)m0*60))[i];
    if (tid < 80) {
        int v = v0 + tid / 5;
        wl[tid] = (v < NV) ? ldf(weights, v*5 + tid % 5, f32) : 0.f;
    }
    for (int i = tid; i < BM*3; i += 512)            // FIX: full coverage
        tl[i] = ldf(transl, (long)m0*3 + i, f32);
    if (tid >= 128 && tid < 176) {
        int i = tid - 128;
        vtl[i] = ((long)v0*3 + i < N3) ? ldf(v_template, (long)v0*3 + i, f32) : 0.f;
    }

    const __hip_bfloat16* abase = Act + (long)(m0 + fr)*KTOT + quad*8;
    const __hip_bfloat16* bbase = Wb  + (long)(n0 + fr)*KTOT + quad*8;

    floatx4 acc[4][3];
#pragma unroll
    for (int q = 0; q < 4; ++q)
#pragma unroll
        for (int t = 0; t < 3; ++t) acc[q][t] = (floatx4){0.f,0.f,0.f,0.f};

    if (wave < 6) {          // 2 K-steps: s = wave*2, wave*2+1
        int s0 = wave * 2;
        short8 Af[2][4], Bf[2][3];
#pragma unroll
        for (int i = 0; i < 2; ++i) {
            int s = s0 + i;
#pragma unroll
            for (int q = 0; q < 4; ++q)
                Af[i][q] = *(const short8*)(abase + (long)q*16*KTOT + s*32);
#pragma unroll
            for (int t = 0; t < 3; ++t)
                Bf[i][t] = *(const short8*)(bbase + (long)t*16*KTOT + s*32);
        }
#pragma unroll
        for (int i = 0; i < 2; ++i)
#pragma unroll
            for (int q = 0; q < 4; ++q)
#pragma unroll
                for (int t = 0; t < 3; ++t)
                    acc[q][t] = __builtin_amdgcn_mfma_f32_16x16x32_bf16(Af[i][q], Bf[i][t], acc[q][t], 0, 0, 0);
    } else {                 // 1 K-step: s = 12 + (wave-6)
        int s = 12 + (wave - 6);
        short8 Af[4], Bf[3];
#pragma unroll
        for (int q = 0; q < 4; ++q)
            Af[q] = *(const short8*)(abase + (long)q*16*KTOT + s*32);
#pragma unroll
        for (int t = 0; t < 3; ++t)
            Bf[t] = *(const short8*)(bbase + (long)t*16*KTOT + s*32);
#pragma unroll
        for (int q = 0; q < 4; ++q)
#pragma unroll
            for (int t = 0; t < 3; ++t)
                acc[q][t] = __builtin_amdgcn_mfma_f32_16x16x32_bf16(Af[q], Bf[t], acc[q][t], 0, 0, 0);
    }

    // tree reduction: waves 0-3 write tiles, waves 4-7 add
    if (wave < 4) {
#pragma unroll
        for (int q = 0; q < 4; ++q)
#pragma unroll
            for (int t = 0; t < 3; ++t)
#pragma unroll
                for (int rr = 0; rr < 4; ++rr)
                    tile[wave][(q*16 + quad*4 + rr)*49 + t*16 + fr] = acc[q][t][rr];
    }
    __syncthreads();
    if (wave >= 4) {
        float* tw = tile[wave - 4];
#pragma unroll
        for (int q = 0; q < 4; ++q)
#pragma unroll
            for (int t = 0; t < 3; ++t)
#pragma unroll
                for (int rr = 0; rr < 4; ++rr)
                    tw[(q*16 + quad*4 + rr)*49 + t*16 + fr] += acc[q][t][rr];
    }
    __syncthreads();

    // LBS epilogue: thread = (m-row, eighth of 16 verts) -> 6 consecutive f32
    int m = tid >> 3, idx = tid & 7;
    const float* A = &Al[m*60];
    long obase = ((long)(m0 + m)*NV + v0)*3;
#pragma unroll
    for (int vi = 0; vi < 2; ++vi) {
        int vloc = idx*2 + vi;
        int v = v0 + vloc;
        if (v >= NV) break;
        int o = m*49 + vloc*3;
        float p0 = tile[0][o+0] + tile[1][o+0] + tile[2][o+0] + tile[3][o+0] + vtl[vloc*3 + 0];
        float p1 = tile[0][o+1] + tile[1][o+1] + tile[2][o+1] + tile[3][o+1] + vtl[vloc*3 + 1];
        float p2 = tile[0][o+2] + tile[1][o+2] + tile[2][o+2] + tile[3][o+2] + vtl[vloc*3 + 2];
        float w0 = wl[vloc*5+0], w1 = wl[vloc*5+1], w2 = wl[vloc*5+2];
        float w3 = wl[vloc*5+3], w4 = wl[vloc*5+4];
#pragma unroll
        for (int c = 0; c < 3; ++c) {
            float t0 = w0*A[c*4+0] + w1*A[12+c*4+0] + w2*A[24+c*4+0] + w3*A[36+c*4+0] + w4*A[48+c*4+0];
            float t1 = w0*A[c*4+1] + w1*A[12+c*4+1] + w2*A[24+c*4+1] + w3*A[36+c*4+1] + w4*A[48+c*4+1];
            float t2 = w0*A[c*4+2] + w1*A[12+c*4+2] + w2*A[24+c*4+2] + w3*A[36+c*4+2] + w4*A[48+c*4+2];
            float t3 = w0*A[c*4+3] + w1*A[12+c*4+3] + w2*A[24+c*4+3] + w3*A[36+c*4+3] + w4*A[48+c*4+3];
            float val = t0*p0 + t1*p1 + t2*p2 + t3 + tl[m*3 + c];
            stf(out, obase + vloc*3 + c, val, f32);
        }
    }
}

// Fallback (small ws): register-direct from raw inputs (round-7 structure).
__global__ __launch_bounds__(256) void k_gemm_lbs_small(
        const __hip_bfloat16* __restrict__ Act,
        const void* __restrict__ shapedirs,
        const void* __restrict__ posedirs,
        const void* __restrict__ v_template,
        const float* __restrict__ Amat,
        const void* __restrict__ weights,
        const void* __restrict__ transl,
        const int* __restrict__ flags,
        void* __restrict__ out) {
    __shared__ float tileS[4][16*49 + 4];
    __shared__ float AlS[4][960];
    __shared__ float wl[80];
    __shared__ __align__(16) __hip_bfloat16 Bs2[BN * 64];

    int f32 = flags[0];
    int tid = threadIdx.x;
    int wave = tid >> 6, lane = tid & 63;
    int fr = lane & 15, quad = lane >> 4;
    int m0 = blockIdx.x * 256;
    int n0 = blockIdx.y * BN;
    int v0 = blockIdx.y * 16;

    if (tid < 80) {
        int v = v0 + tid / 5;
        wl[tid] = (v < NV) ? ldf(weights, v*5 + tid % 5, f32) : 0.f;
    }
    for (int i = tid; i < BN * 64; i += 256) {
        int n = i >> 6, kk = i & 63;
        int nc = min(n0 + n, N3 - 1);
        float val = 0.f;
        if (kk < 16)      val = ldf(shapedirs, (long)nc*KBETA + 384 + kk, f32);
        else if (kk < 52) val = ldf(posedirs, (long)(kk-16)*N3 + nc, f32);
        Bs2[n*64 + kk] = __float2bfloat16(val);
    }
    __syncthreads();

    const __hip_bfloat16* arow[4];
#pragma unroll
    for (int sub = 0; sub < 4; ++sub)
        arow[sub] = Act + (long)(m0 + wave*64 + sub*16 + fr) * KTOT;
    int nr[3];
#pragma unroll
    for (int t = 0; t < 3; ++t) nr[t] = min(n0 + t*16 + fr, N3 - 1);

    floatx4 acc[4][3];
#pragma unroll
    for (int sub = 0; sub < 4; ++sub)
#pragma unroll
        for (int t = 0; t < 3; ++t) acc[sub][t] = (floatx4){0.f,0.f,0.f,0.f};

#pragma unroll
    for (int s = 0; s < 14; ++s) {
        short8 bb[3];
#pragma unroll
        for (int t = 0; t < 3; ++t) {
            if (s < 12) bb[t] = ld8bf(shapedirs, (long)nr[t]*KBETA + s*32 + quad*8, f32);
            else        bb[t] = *(short8*)&Bs2[(t*16 + fr)*64 + (s-12)*32 + quad*8];
        }
#pragma unroll
        for (int sub = 0; sub < 4; ++sub) {
            short8 a = *(const short8*)(arow[sub] + s*32 + quad*8);
#pragma unroll
            for (int t = 0; t < 3; ++t)
                acc[sub][t] = __builtin_amdgcn_mfma_f32_16x16x32_bf16(a, bb[t], acc[sub][t], 0, 0, 0);
        }
    }

    int vloc = fr, rgrp = quad;
    int v = v0 + vloc;
    float tpl0 = 0.f, tpl1 = 0.f, tpl2 = 0.f;
    if (v < NV) {
        tpl0 = ldf(v_template, v*3 + 0, f32);
        tpl1 = ldf(v_template, v*3 + 1, f32);
        tpl2 = ldf(v_template, v*3 + 2, f32);
    }
    float w0 = wl[vloc*5+0], w1 = wl[vloc*5+1], w2 = wl[vloc*5+2];
    float w3 = wl[vloc*5+3], w4 = wl[vloc*5+4];
    for (int sub = 0; sub < 4; ++sub) {
#pragma unroll
        for (int t = 0; t < 3; ++t)
#pragma unroll
            for (int rr = 0; rr < 4; ++rr)
                tileS[wave][(quad*4 + rr)*49 + t*16 + fr] = acc[sub][t][rr];
        for (int i = lane; i < 960; i += 64)
            AlS[wave][i] = Amat[(long)(m0 + wave*64 + sub*16)*60 + i];
        __syncthreads();
        if (v < NV) {
#pragma unroll
            for (int rr = 0; rr < 4; ++rr) {
                int mloc = rgrp*4 + rr;
                long m = m0 + wave*64 + sub*16 + mloc;
                float p0 = tileS[wave][mloc*49 + vloc*3 + 0] + tpl0;
                float p1 = tileS[wave][mloc*49 + vloc*3 + 1] + tpl1;
                float p2 = tileS[wave][mloc*49 + vloc*3 + 2] + tpl2;
                const float* A = &AlS[wave][mloc*60];
#pragma unroll
                for (int c = 0; c < 3; ++c) {
                    float t0 = w0*A[c*4+0] + w1*A[12+c*4+0] + w2*A[24+c*4+0] + w3*A[36+c*4+0] + w4*A[48+c*4+0];
                    float t1 = w0*A[c*4+1] + w1*A[12+c*4+1] + w2*A[24+c*4+1] + w3*A[36+c*4+1] + w4*A[48+c*4+1];
                    float t2 = w0*A[c*4+2] + w1*A[12+c*4+2] + w2*A[24+c*4+2] + w3*A[36+c*4+2] + w4*A[48+c*4+2];
                    float t3 = w0*A[c*4+3] + w1*A[12+c*4+3] + w2*A[24+c*4+3] + w3*A[36+c*4+3] + w4*A[48+c*4+3];
                    float val = t0*p0 + t1*p1 + t2*p2 + t3 + ldf(transl, m*3 + c, f32);
                    stf(out, (m*NV + v)*3 + c, val, f32);
                }
            }
        }
        __syncthreads();
    }
}

__global__ __launch_bounds__(64) void k_lmk(const void* __restrict__ verts,
                                            const void* __restrict__ bary,
                                            const int* __restrict__ faces,
                                            const void* __restrict__ lmk_idx,
                                            const void* __restrict__ transl,
                                            const float* __restrict__ reg,
                                            const void* __restrict__ shape_p,
                                            void* __restrict__ out) {
    int f32 = probe_f32(shape_p);
    int i64 = probe_i64(lmk_idx);
    int b = blockIdx.x, tid = threadIdx.x;
    if (b == 0 && tid == 63)
        stf(out, (long)BATCH*NV*3 + (long)BATCH*NLMK*3, reg[0], f32);
    if (tid >= NLMK) return;
    int f = i64 ? (int)((const long long*)lmk_idx)[tid]
                : ((const int*)lmk_idx)[tid];
    float acc[3] = {0.f, 0.f, 0.f};
    float bsum = 0.f;
    for (int fi = 0; fi < 3; ++fi) {
        int vi = faces[f*3 + fi];
        float bc = ldf(bary, tid*3 + fi, f32);
        bsum += bc;
#pragma unroll
        for (int c = 0; c < 3; ++c)
            acc[c] += bc * ldf(verts, ((long)b*NV + vi)*3 + c, f32);
    }
#pragma unroll
    for (int c = 0; c < 3; ++c) {
        float val = acc[c] + (1.f - bsum) * ldf(transl, b*3 + c, f32);
        stf(out, (long)BATCH*NV*3 + ((long)b*NLMK + tid)*3 + c, val, f32);
    }
}

extern "C" void kernel_launch(void* const* d_in, const int* in_sizes, int n_in,
                              void* d_out, int out_size, void* d_ws, size_t ws_size,
                              hipStream_t stream) {
    const void* shape_p   = d_in[0];
    const void* expr_p    = d_in[1];
    const void* grot      = d_in[2];
    const void* neck      = d_in[3];
    const void* jaw       = d_in[4];
    const void* eye       = d_in[5];
    const void* transl    = d_in[6];
    const void* v_templ   = d_in[7];
    const void* shapedirs = d_in[8];
    const void* posedirs  = d_in[9];
    const void* Jreg      = d_in[10];
    const void* weights   = d_in[11];
    const void* bary      = d_in[12];
    const int*  faces     = (const int*)d_in[14];
    const void* lmk_idx   = d_in[15];

    char* ws = (char*)d_ws;
    float* JS      = (float*)(ws + WS_JS);
    float* baseJ   = (float*)(ws + WS_BASEJ);
    float* reg     = (float*)(ws + WS_REG);
    int*   flags   = (int*)(ws + WS_FLAGS);
    float* Amat    = (float*)(ws + WS_AMAT);
    __hip_bfloat16* Act = (__hip_bfloat16*)(ws + WS_ACT);
    __hip_bfloat16* Wb  = (__hip_bfloat16*)(ws + WS_WB);
    float* PART    = (float*)d_out;   // scratch before verts are written
    bool big = ws_size >= (size_t)WS_FULL;

    if (big) {
        k_prep<<<CVT_BLKS + 384, 256, 0, stream>>>(shapedirs, posedirs, Jreg, v_templ,
                                                   shape_p, reg, Wb, PART);
        k_js_red<<<24, 256, 0, stream>>>(PART, JS, baseJ);
    } else {
        k_init<<<24, 256, 0, stream>>>((float*)ws, shape_p, lmk_idx, flags);
        k_js_atomic<<<dim3(3, 64), 256, 0, stream>>>(Jreg, shapedirs, v_templ, flags, JS, baseJ);
    }
    k_batch<<<BATCH, 64, 0, stream>>>(shape_p, expr_p, grot, neck, jaw, eye,
                                      JS, baseJ, Act, Amat, reg);
    if (big) {
        // swizzled 1D grid: 40 panel-groups * 8 xcd * 16 m = 5120 (96 no-ops)
        k_gemm_lbs_big<<<5120, 512, 0, stream>>>(Act, Wb, v_templ, Amat,
                                                 weights, transl, shape_p, d_out);
    } else {
        dim3 grid(BATCH/256, (N3 + BN - 1)/BN);
        k_gemm_lbs_small<<<grid, 256, 0, stream>>>(Act, shapedirs, posedirs, v_templ,
                                                   Amat, weights, transl, flags, d_out);
    }
    k_lmk<<<BATCH, 64, 0, stream>>>(d_out, bary, faces, lmk_idx, transl, reg, shape_p, d_out);
}